// Round 18
// baseline (238.104 us; speedup 1.0000x reference)
//
#include <hip/hip_runtime.h>
#include <stdint.h>

#define B_   16
#define S_   1024
#define D_   512
#define H_   8
#define DH_  64
#define DFF_ 2048
#define M_   (B_*S_)     // 16384
#define SD_  (S_*D_)     // 524288
#define NT_  16          // S_/64 KV tiles

typedef unsigned short u16;
typedef unsigned int u32;
typedef __attribute__((ext_vector_type(2))) unsigned int u32x2;
typedef __attribute__((ext_vector_type(4))) unsigned short u16x4;
typedef __attribute__((ext_vector_type(8))) short bf16x8;
typedef __attribute__((ext_vector_type(4))) float f32x4;
typedef __attribute__((ext_vector_type(16))) float f32x16;

#define LOG2E 1.4426950408889634f

#if defined(__has_builtin)
#if __has_builtin(__builtin_amdgcn_permlane32_swap)
#define HAVE_PLS 1
#endif
#endif

__device__ __forceinline__ u16 f2bf(float f) {
  union { float f; uint32_t u; } x{f};
  uint32_t r = x.u + 0x7fffu + ((x.u >> 16) & 1u);
  return (u16)(r >> 16);
}

__device__ __forceinline__ float bf2f(u16 v) {
  union { uint32_t u; float f; } x{(uint32_t)v << 16};
  return x.f;
}

// pack hi16(a), hi16(b) -> dword (truncating bf16 pair) via v_perm_b32
__device__ __forceinline__ u32 pk2(float lo, float hi) {
  union { float f; u32 u; } a{lo}, b{hi};
  return __builtin_amdgcn_perm(b.u, a.u, 0x07060302u);
}

__device__ __forceinline__ float exp2fast(float x) {
#if __has_builtin(__builtin_amdgcn_exp2f)
  return __builtin_amdgcn_exp2f(x);
#else
  return exp2f(x);
#endif
}

__device__ __forceinline__ void gload16(const u16* g, u16* l) {
  __builtin_amdgcn_global_load_lds(
      (const __attribute__((address_space(1))) uint32_t*)g,
      (__attribute__((address_space(3))) uint32_t*)l, 16, 0, 0);
}

__device__ __forceinline__ int swz3(int r) { return (r & 7) ^ ((r >> 3) & 7); }

// ---------------- fused prep: cast x + all 6 weight transposes, one dispatch ----------------
__global__ __launch_bounds__(256) void prep_kernel(
    const float* __restrict__ x, u16* __restrict__ xb,
    const float* __restrict__ wq, const float* __restrict__ wk,
    const float* __restrict__ wv, const float* __restrict__ wo,
    const float* __restrict__ w1, const float* __restrict__ w2,
    u16* __restrict__ wqkvT, u16* __restrict__ woT,
    u16* __restrict__ w1T, u16* __restrict__ w2T) {
  int bid = blockIdx.x, tid = threadIdx.x;
  if (bid < 8192) {
    int i = bid * 256 + tid;
    f32x4 v = ((const f32x4*)x)[i];
    u16x4 o = { f2bf(v[0]), f2bf(v[1]), f2bf(v[2]), f2bf(v[3]) };
    ((u16x4*)xb)[i] = o;
    return;
  }
  bid -= 8192;
  const float* W; u16* WT; int K, N, bx, by;
  if (bid < 1024) {
    int which = bid >> 8;
    W  = (which == 0) ? wq : (which == 1) ? wk : (which == 2) ? wv : wo;
    WT = (which == 3) ? woT : (wqkvT + (size_t)which * 512 * 512);
    K = 512; N = 512;
    int r = bid & 255; bx = r & 15; by = r >> 4;
  } else if (bid < 2048) {
    int r = bid - 1024; W = w1; WT = w1T; K = 512; N = 2048;
    bx = r & 63; by = r >> 6;
  } else {
    int r = bid - 2048; W = w2; WT = w2T; K = 2048; N = 512;
    bx = r & 15; by = r >> 4;
  }
  __shared__ float t[32][33];
  int n0 = bx * 32, k0 = by * 32;
  int tx = tid & 31, ty = tid >> 5;
  #pragma unroll
  for (int i = 0; i < 4; i++)
    t[ty + 8*i][tx] = W[(size_t)(k0 + ty + 8*i) * N + n0 + tx];
  __syncthreads();
  #pragma unroll
  for (int i = 0; i < 4; i++)
    WT[(size_t)(n0 + ty + 8*i) * K + k0 + tx] = f2bf(t[tx][ty + 8*i]);
}

// ================= 128x128 GEMM, 1 barrier per K-tile, swizzled LDS =================
// MODE 0: bf16 out (+RELU). MODE 1: bf16 residual-sum out + fused LN partials.
template<int MODE, bool RELU, bool RESB>
__global__ __launch_bounds__(256) void gemm_kernel(
    const u16* __restrict__ A, const u16* __restrict__ WT,
    const float* __restrict__ bias0, const float* __restrict__ res,
    const u16* __restrict__ resB,
    u16* __restrict__ out0,
    float* __restrict__ partOut, int K, int N, int nx, int ypg) {
  __shared__ u16 lA[2][128 * 32];
  __shared__ u16 lB[2][128 * 32];
  __shared__ float lred[8];
  int tid = threadIdx.x;
  int lane = tid & 63, wid = tid >> 6;
  int wr = wid >> 1, wc = wid & 1;
  int lrow = lane & 15, kg = lane >> 4;

  int dd = blockIdx.x;
  int cc = dd & 7, jj = dd >> 3;
  int bx = jj % nx, by = cc * ypg + jj / nx;
  int m0 = by * 128, n0 = bx * 128;

  int r0 = tid >> 2;
  int c0s = ((tid & 3) ^ ((r0 >> 1) & 3)) * 8;   // inverse-swizzled source col
  const u16* agp = A  + (size_t)m0 * K;
  const u16* bgp = WT + (size_t)n0 * K;

  int aoff[4], boff[4];
  #pragma unroll
  for (int mi = 0; mi < 4; mi++) {
    int row = wr*64 + mi*16 + lrow;
    aoff[mi] = row*32 + ((kg ^ ((row >> 1) & 3)) * 8);
  }
  #pragma unroll
  for (int ni = 0; ni < 4; ni++) {
    int row = wc*64 + ni*16 + lrow;
    boff[ni] = row*32 + ((kg ^ ((row >> 1) & 3)) * 8);
  }

  f32x4 z = {0.f, 0.f, 0.f, 0.f};
  f32x4 acc[4][4];
  #pragma unroll
  for (int mi = 0; mi < 4; mi++)
    #pragma unroll
    for (int ni = 0; ni < 4; ni++) acc[mi][ni] = z;

#define STAGE_G(buf, kt) do { \
    gload16(agp + (size_t)r0 * K + (kt) + c0s,        &lA[buf][tid * 8]); \
    gload16(agp + (size_t)(r0 + 64) * K + (kt) + c0s, &lA[buf][2048 + tid * 8]); \
    gload16(bgp + (size_t)r0 * K + (kt) + c0s,        &lB[buf][tid * 8]); \
    gload16(bgp + (size_t)(r0 + 64) * K + (kt) + c0s, &lB[buf][2048 + tid * 8]); \
  } while (0)

  STAGE_G(0, 0);

  int nk = K / 32;
  int cur = 0;
  for (int t = 0; t < nk; t++) {
    __syncthreads();
    if (t + 1 < nk) STAGE_G(cur ^ 1, (t + 1) * 32);
    bf16x8 af[4], bfv[4];
    #pragma unroll
    for (int mi = 0; mi < 4; mi++)
      af[mi] = *(const bf16x8*)&lA[cur][aoff[mi]];
    #pragma unroll
    for (int ni = 0; ni < 4; ni++)
      bfv[ni] = *(const bf16x8*)&lB[cur][boff[ni]];
    __builtin_amdgcn_s_setprio(1);
    #pragma unroll
    for (int mi = 0; mi < 4; mi++)
      #pragma unroll
      for (int ni = 0; ni < 4; ni++)
        acc[mi][ni] = __builtin_amdgcn_mfma_f32_16x16x32_bf16(af[mi], bfv[ni], acc[mi][ni], 0, 0, 0);
    __builtin_amdgcn_s_setprio(0);
    cur ^= 1;
  }
#undef STAGE_G

  float s_acc = 0.f, q_acc = 0.f;
  #pragma unroll
  for (int mi = 0; mi < 4; mi++)
    #pragma unroll
    for (int ni = 0; ni < 4; ni++) {
      int col = n0 + wc*64 + ni*16 + lrow;
      float bv = bias0[col];
      #pragma unroll
      for (int r = 0; r < 4; r++) {
        int row = m0 + wr*64 + mi*16 + kg*4 + r;
        float v = acc[mi][ni][r] + bv;
        if (RELU) v = fmaxf(v, 0.f);
        size_t off = (size_t)row * N + col;
        if (MODE == 1) {
          float rv = RESB ? bf2f(resB[off]) : res[off];
          float tv = v + rv;
          out0[off] = f2bf(tv);
          s_acc += tv;
          q_acc += tv * tv;
        } else {
          out0[off] = f2bf(v);
        }
      }
    }

  if (MODE == 1) {
    #pragma unroll
    for (int dsh = 1; dsh < 64; dsh <<= 1) {
      s_acc += __shfl_xor(s_acc, dsh);
      q_acc += __shfl_xor(q_acc, dsh);
    }
    if (lane == 0) { lred[wid*2] = s_acc; lred[wid*2+1] = q_acc; }
    __syncthreads();
    if (tid == 0) {
      int batch = by >> 3;
      int pidx = batch*32 + (by & 7)*nx + bx;
      partOut[pidx*2]   = lred[0]+lred[2]+lred[4]+lred[6];
      partOut[pidx*2+1] = lred[1]+lred[3]+lred[5]+lred[7];
    }
  }
}

// ================= 256x256 8-wave BK=32 GEMM (FFN1), 1 barrier per K-tile, swizzled =================
template<bool RELU>
__global__ __launch_bounds__(512, 2) void gemm256_kernel(
    const u16* __restrict__ A, const u16* __restrict__ WT,
    const float* __restrict__ bias0,
    u16* __restrict__ out0, int K, int N, int nx, int ypg) {
  __shared__ u16 lA[2][8192];   // [row 256][32], slot-swizzled
  __shared__ u16 lB[2][8192];
  int tid = threadIdx.x, lane = tid & 63;
  int wid = tid >> 6, wm = wid >> 2, wn = wid & 3;
  int l16 = lane & 15, kg4 = lane >> 4;

  int d = blockIdx.x;
  int c = d & 7, j = d >> 3;
  int x = j % nx, y = c * ypg + j / nx;
  int m0 = y * 256, n0 = x * 256;

  const u16* agp = A  + (size_t)m0 * K;
  const u16* bgp = WT + (size_t)n0 * K;
  int srow = tid >> 2;                              // 0..127 (g=1 adds 128; swizzle invariant)
  int scs  = ((tid & 3) ^ ((srow >> 1) & 3)) * 8;   // inverse-swizzled source col

  // loop-invariant swizzled fragment offsets
  int aoff[8], boff[4];
  #pragma unroll
  for (int mg = 0; mg < 8; mg++) {
    int row = wm*128 + mg*16 + l16;
    aoff[mg] = row*32 + ((kg4 ^ ((row >> 1) & 3)) * 8);
  }
  #pragma unroll
  for (int ni = 0; ni < 4; ni++) {
    int row = wn*64 + ni*16 + l16;
    boff[ni] = row*32 + ((kg4 ^ ((row >> 1) & 3)) * 8);
  }

  f32x4 z = {0.f, 0.f, 0.f, 0.f};
  f32x4 acc[8][4];
  #pragma unroll
  for (int mg = 0; mg < 8; mg++)
    #pragma unroll
    for (int ni = 0; ni < 4; ni++) acc[mg][ni] = z;

#define STG256(buf, kt) do { \
    gload16(agp + (size_t)srow * K + (kt) + scs,         &lA[buf][tid * 8]); \
    gload16(agp + (size_t)(srow + 128) * K + (kt) + scs, &lA[buf][4096 + tid * 8]); \
    gload16(bgp + (size_t)srow * K + (kt) + scs,         &lB[buf][tid * 8]); \
    gload16(bgp + (size_t)(srow + 128) * K + (kt) + scs, &lB[buf][4096 + tid * 8]); \
  } while (0)

  STG256(0, 0);

  int nk = K / 32;
  int cur = 0;
  for (int t = 0; t < nk; t++) {
    __syncthreads();                 // drains prior DMAs; separates read/overwrite of cur^1
    if (t + 1 < nk) STG256(cur ^ 1, (t + 1) * 32);
    bf16x8 bfv[4];
    #pragma unroll
    for (int ni = 0; ni < 4; ni++)
      bfv[ni] = *(const bf16x8*)&lB[cur][boff[ni]];
    #pragma unroll
    for (int mg = 0; mg < 8; mg++) {
      bf16x8 af = *(const bf16x8*)&lA[cur][aoff[mg]];
      __builtin_amdgcn_s_setprio(1);
      #pragma unroll
      for (int ni = 0; ni < 4; ni++)
        acc[mg][ni] = __builtin_amdgcn_mfma_f32_16x16x32_bf16(af, bfv[ni], acc[mg][ni], 0, 0, 0);
      __builtin_amdgcn_s_setprio(0);
    }
    cur ^= 1;
  }
#undef STG256

  #pragma unroll
  for (int mg = 0; mg < 8; mg++)
    #pragma unroll
    for (int ni = 0; ni < 4; ni++) {
      int col = n0 + wn*64 + ni*16 + l16;
      float bv = bias0[col];
      #pragma unroll
      for (int r = 0; r < 4; r++) {
        int row = m0 + wm*128 + mg*16 + kg4*4 + r;
        float v = acc[mg][ni][r] + bv;
        if (RELU) v = fmaxf(v, 0.f);
        out0[(size_t)row * N + col] = f2bf(v);
      }
    }
}

// ================= 128x128 QKV GEMM (N=1536 split into Q/K/V, Q scaled), swizzled LDS =================
__global__ __launch_bounds__(256) void gemm128_qkv_kernel(
    const u16* __restrict__ A, const u16* __restrict__ WT,
    const float* __restrict__ bq, const float* __restrict__ bk,
    const float* __restrict__ bv,
    u16* __restrict__ Qb, u16* __restrict__ Kb, u16* __restrict__ Vb,
    int K, int nx, int ypg) {
  __shared__ u16 lA[2][128 * 32];
  __shared__ u16 lB[2][128 * 32];
  int tid = threadIdx.x;
  int lane = tid & 63, wid = tid >> 6;
  int wr = wid >> 1, wc = wid & 1;
  int lrow = lane & 15, kg = lane >> 4;

  int dd = blockIdx.x;
  int cc = dd & 7, jj = dd >> 3;
  int bx = jj % nx, by = cc * ypg + jj / nx;
  int m0 = by * 128, n0 = bx * 128;

  int r0 = tid >> 2;
  int c0s = ((tid & 3) ^ ((r0 >> 1) & 3)) * 8;
  const u16* agp = A  + (size_t)m0 * K;
  const u16* bgp = WT + (size_t)n0 * K;

  int aoff[4], boff[4];
  #pragma unroll
  for (int mi = 0; mi < 4; mi++) {
    int row = wr*64 + mi*16 + lrow;
    aoff[mi] = row*32 + ((kg ^ ((row >> 1) & 3)) * 8);
  }
  #pragma unroll
  for (int ni = 0; ni < 4; ni++) {
    int row = wc*64 + ni*16 + lrow;
    boff[ni] = row*32 + ((kg ^ ((row >> 1) & 3)) * 8);
  }

  f32x4 z = {0.f, 0.f, 0.f, 0.f};
  f32x4 acc[4][4];
  #pragma unroll
  for (int mi = 0; mi < 4; mi++)
    #pragma unroll
    for (int ni = 0; ni < 4; ni++) acc[mi][ni] = z;

#define STAGE_G(buf, kt) do { \
    gload16(agp + (size_t)r0 * K + (kt) + c0s,        &lA[buf][tid * 8]); \
    gload16(agp + (size_t)(r0 + 64) * K + (kt) + c0s, &lA[buf][2048 + tid * 8]); \
    gload16(bgp + (size_t)r0 * K + (kt) + c0s,        &lB[buf][tid * 8]); \
    gload16(bgp + (size_t)(r0 + 64) * K + (kt) + c0s, &lB[buf][2048 + tid * 8]); \
  } while (0)

  STAGE_G(0, 0);

  int nk = K / 32;
  int cur = 0;
  for (int t = 0; t < nk; t++) {
    __syncthreads();
    if (t + 1 < nk) STAGE_G(cur ^ 1, (t + 1) * 32);
    bf16x8 af[4], bfv[4];
    #pragma unroll
    for (int mi = 0; mi < 4; mi++)
      af[mi] = *(const bf16x8*)&lA[cur][aoff[mi]];
    #pragma unroll
    for (int ni = 0; ni < 4; ni++)
      bfv[ni] = *(const bf16x8*)&lB[cur][boff[ni]];
    __builtin_amdgcn_s_setprio(1);
    #pragma unroll
    for (int mi = 0; mi < 4; mi++)
      #pragma unroll
      for (int ni = 0; ni < 4; ni++)
        acc[mi][ni] = __builtin_amdgcn_mfma_f32_16x16x32_bf16(af[mi], bfv[ni], acc[mi][ni], 0, 0, 0);
    __builtin_amdgcn_s_setprio(0);
    cur ^= 1;
  }
#undef STAGE_G

  int seg = n0 >> 9;                       // 0=Q, 1=K, 2=V
  const float* bp = (seg == 0) ? bq : (seg == 1) ? bk : bv;
  u16* op = (seg == 0) ? Qb : (seg == 1) ? Kb : Vb;
  float aeff = (seg == 0) ? 0.125f * LOG2E : 1.0f;

  #pragma unroll
  for (int mi = 0; mi < 4; mi++)
    #pragma unroll
    for (int ni = 0; ni < 4; ni++) {
      int col = n0 + wc*64 + ni*16 + lrow;
      int ocol = col & 511;
      float bvv = bp[ocol];
      #pragma unroll
      for (int r = 0; r < 4; r++) {
        int row = m0 + wr*64 + mi*16 + kg*4 + r;
        float v = (acc[mi][ni][r] + bvv) * aeff;
        op[(size_t)row * 512 + ocol] = f2bf(v);
      }
    }
}

// ---------------- flash attention v11: 8-wave blocks, 256 q-rows, shared K/V staging ----------------
__global__ __launch_bounds__(512) void attn_kernel(
    const u16* __restrict__ Q, const u16* __restrict__ Km,
    const u16* __restrict__ Vm, const float* __restrict__ mask,
    u16* __restrict__ ctx) {
  __shared__ u16 lK[2][4096];     // [key 64][dh 64], dword-swizzled, 128B rows
  __shared__ u16 lV[2][4096];     // [dh 64][key 64] transposed, dword-swizzled
  __shared__ float lBias[1024];
  int tid = threadIdx.x, lane = tid & 63, wid = tid >> 6;   // wid 0..7
  int la = lane & 31, hi = lane >> 5;
  int wg = blockIdx.x;
  int xcd = wg & 7, idx = wg >> 3;      // idx 0..63
  int bh = xcd * 16 + (idx & 15);
  int qt = idx >> 4;                    // 0..3 (256-row q tiles)
  int b = bh >> 3, h = bh & 7;
  bool vwave = (wid < 4);               // wave-uniform staging split
  int tid2 = tid & 255;                 // K-staging index for waves 4-7

  const u16* qp = Q + (size_t)(b*S_ + qt*256 + wid*32 + la) * D_ + h*DH_ + hi*8;
  bf16x8 qf[4];
  #pragma unroll
  for (int c = 0; c < 4; c++) qf[c] = *(const bf16x8*)(qp + c*16);

  int krow = tid2 >> 3;                 // 0..31 (K rows, +32 second call)
  int kcol = 8 * (tid2 & 7);
  int kc0 = kcol ^ (swz3(krow) << 3);
  int kc1 = kcol ^ (swz3(krow + 32) << 3);
  int va = tid & 7, vp = (tid >> 3) & 31;   // V staging map (waves 0-3: tid<256)
  const u16* kbase = Km + ((size_t)b*S_) * D_ + h*DH_;
  const u16* vbase = Vm + ((size_t)b*S_) * D_ + h*DH_ + 8*va;

#define STAGE_K(buf, tt) do { \
    const u16* kt_ = kbase + (size_t)(tt)*64*D_; \
    gload16(kt_ + (size_t)krow*D_ + kc0,        &lK[buf][tid2*8]); \
    gload16(kt_ + (size_t)(krow+32)*D_ + kc1,   &lK[buf][2048 + tid2*8]); \
  } while (0)
#define LOAD_V(tt) do { \
    const u16* vt_ = vbase + (size_t)((tt)*64 + 2*vp) * D_; \
    nv0 = *(const bf16x8*)vt_; nv1 = *(const bf16x8*)(vt_ + D_); \
  } while (0)
#define WRITE_V(buf) do { \
    u32* lVd_ = (u32*)lV[buf]; \
    _Pragma("unroll") \
    for (int jv = 0; jv < 8; jv++) { \
      int row_ = 8*va + jv; \
      u32 pv_ = (u32)(u16)nv0[jv] | ((u32)(u16)nv1[jv] << 16); \
      lVd_[row_*32 + (vp ^ (swz3(row_) << 2))] = pv_; \
    } \
  } while (0)

  int swk0 = swz3(la) << 2, swk1 = swz3(la + 32) << 2;
  f32x16 oc0, oc1;
  #pragma unroll
  for (int i = 0; i < 16; i++) { oc0[i] = 0.f; oc1[i] = 0.f; }
  float lsum = 0.f;

#define QKT(d0, d1, tt) do { \
    _Pragma("unroll") \
    for (int rq = 0; rq < 4; rq++) { \
      f32x4 bb0 = *(const f32x4*)&lBias[(tt)*64 + rq*8 + hi*4]; \
      f32x4 bb1 = *(const f32x4*)&lBias[(tt)*64 + 32 + rq*8 + hi*4]; \
      _Pragma("unroll") \
      for (int jj = 0; jj < 4; jj++) { d0[rq*4+jj] = bb0[jj]; d1[rq*4+jj] = bb1[jj]; } \
    } \
    { const u16* lkb_ = lK[(tt)&1]; \
      __builtin_amdgcn_s_setprio(1); \
      _Pragma("unroll") \
      for (int c_ = 0; c_ < 4; c_++) { \
        int dwb_ = c_*8 + hi*4; \
        bf16x8 kf0_ = *(const bf16x8*)&lkb_[la*64 + ((dwb_ ^ swk0) << 1)]; \
        bf16x8 kf1_ = *(const bf16x8*)&lkb_[(la+32)*64 + ((dwb_ ^ swk1) << 1)]; \
        d0 = __builtin_amdgcn_mfma_f32_32x32x16_bf16(kf0_, qf[c_], d0, 0, 0, 0); \
        d1 = __builtin_amdgcn_mfma_f32_32x32x16_bf16(kf1_, qf[c_], d1, 0, 0, 0); \
      } \
      __builtin_amdgcn_s_setprio(0); } \
  } while (0)

#define SOFTPV(s0v, s1v, tt) do { \
    float rsp_[4] = {0.f, 0.f, 0.f, 0.f}; \
    _Pragma("unroll") \
    for (int i_ = 0; i_ < 16; i_++) { float e_ = exp2fast(s0v[i_]); s0v[i_] = e_; rsp_[i_ & 3] += e_; } \
    _Pragma("unroll") \
    for (int i_ = 0; i_ < 16; i_++) { float e_ = exp2fast(s1v[i_]); s1v[i_] = e_; rsp_[i_ & 3] += e_; } \
    lsum += (rsp_[0] + rsp_[1]) + (rsp_[2] + rsp_[3]); \
    { const u16* lvb_ = lV[(tt)&1]; \
      __builtin_amdgcn_s_setprio(1); \
      _Pragma("unroll") \
      for (int cc_ = 0; cc_ < 4; cc_++) { \
        const int base_ = 8 * (cc_ & 1); \
        float pv_[8]; \
        _Pragma("unroll") \
        for (int k_ = 0; k_ < 8; k_++) pv_[k_] = (cc_ < 2) ? s0v[base_ + k_] : s1v[base_ + k_]; \
        u32 a0_ = pk2(pv_[0], pv_[1]); \
        u32 a1_ = pk2(pv_[2], pv_[3]); \
        u32 b0_ = pk2(pv_[4], pv_[5]); \
        u32 b1_ = pk2(pv_[6], pv_[7]); \
        union { u32 u[4]; bf16x8 v; } pf_; \
        PEXCH(pf_, a0_, a1_, b0_, b1_); \
        _Pragma("unroll") \
        for (int vb_ = 0; vb_ < 2; vb_++) { \
          int row_ = vb_*32 + la; \
          int dwv_ = (cc_*8 + hi*4) ^ (swz3(row_) << 2); \
          bf16x8 vf_ = *(const bf16x8*)&lvb_[row_*64 + (dwv_ << 1)]; \
          if (vb_ == 0) oc0 = __builtin_amdgcn_mfma_f32_32x32x16_bf16(pf_.v, vf_, oc0, 0, 0, 0); \
          else          oc1 = __builtin_amdgcn_mfma_f32_32x32x16_bf16(pf_.v, vf_, oc1, 0, 0, 0); \
        } \
      } \
      __builtin_amdgcn_s_setprio(0); } \
  } while (0)

#ifdef HAVE_PLS
#define PEXCH(pf_, a0_, a1_, b0_, b1_) do { \
    u32x2 r0_ = __builtin_amdgcn_permlane32_swap(a0_, b0_, false, false); \
    u32x2 r1_ = __builtin_amdgcn_permlane32_swap(a1_, b1_, false, false); \
    pf_.u[0] = r0_[0]; pf_.u[1] = r1_[0]; pf_.u[2] = r0_[1]; pf_.u[3] = r1_[1]; \
  } while (0)
#else
#define PEXCH(pf_, a0_, a1_, b0_, b1_) do { \
    u32 sd0_ = hi ? a0_ : b0_, sd1_ = hi ? a1_ : b1_; \
    u32 x0_ = (u32)__shfl_xor((int)sd0_, 32); \
    u32 x1_ = (u32)__shfl_xor((int)sd1_, 32); \
    pf_.u[0] = hi ? x0_ : a0_; \
    pf_.u[1] = hi ? x1_ : a1_; \
    pf_.u[2] = hi ? b0_ : x0_; \
    pf_.u[3] = hi ? b1_ : x1_; \
  } while (0)
#endif

  // ---- prologue: waves 0-3 stage V0 + bias, load V1; waves 4-7 DMA K0,K1 ----
  bf16x8 nv0, nv1;
  if (vwave) {
    f32x4 mv = ((const f32x4*)(mask + (size_t)b*S_))[tid];
    f32x4 bv;
    #pragma unroll
    for (int jj = 0; jj < 4; jj++) bv[jj] = mv[jj] * (-1.0e9f * LOG2E);
    ((f32x4*)lBias)[tid] = bv;
    LOAD_V(0);
    WRITE_V(0);
    LOAD_V(1);
  } else {
    STAGE_K(0, 0);
    STAGE_K(1, 1);
  }
  __syncthreads();

  f32x16 sA0, sA1, sB0, sB1;
  QKT(sA0, sA1, 0);
  __syncthreads();          // all waves done reading lK[0] before iter0 re-DMAs it

  // ---- pipelined main loop, unrolled by 2 (A/B score states) ----
  for (int t = 0; t < NT_; t += 2) {
    if (!vwave) { if (t + 2 < NT_) STAGE_K(t & 1, t + 2); }
    if (vwave) {
      WRITE_V((t + 1) & 1);
      if (t + 2 < NT_) LOAD_V(t + 2);
    }
    QKT(sB0, sB1, t + 1);
    SOFTPV(sA0, sA1, t);
    __syncthreads();
    {
      int u = t + 1;
      if (!vwave) { if (u + 2 < NT_) STAGE_K(u & 1, u + 2); }
      if (vwave) {
        if (u + 1 < NT_) WRITE_V((u + 1) & 1);
        if (u + 2 < NT_) LOAD_V(u + 2);
      }
      if (u + 1 < NT_) QKT(sA0, sA1, u + 1);
      SOFTPV(sB0, sB1, u);
      __syncthreads();
    }
  }
#undef STAGE_K
#undef LOAD_V
#undef WRITE_V
#undef QKT
#undef SOFTPV
#undef PEXCH

  // ---- epilogue ----
  lsum += __shfl_xor(lsum, 32);
  float linv = 1.f / lsum;
  #pragma unroll
  for (int r = 0; r < 16; r++) {
    int qr = (r&3) + 8*(r>>2) + 4*hi;
    float lr = __shfl(linv, qr);
    size_t rowoff = (size_t)(b*S_ + qt*256 + wid*32 + qr) * D_ + h*DH_;
    ctx[rowoff + la]      = f2bf(oc0[r] * lr);
    ctx[rowoff + 32 + la] = f2bf(oc1[r] * lr);
  }
}

// ---------------- LayerNorm apply (bf16 input; partials from GEMM epilogue) ----------------
template<bool WB, bool WF>
__global__ __launch_bounds__(256) void ln_apply_kernel(
    const u16* __restrict__ r, const float* __restrict__ part,
    const float* __restrict__ w, const float* __restrict__ bb,
    float* __restrict__ outF, u16* __restrict__ outB) {
  int b = blockIdx.y, c = blockIdx.x, tid = threadIdx.x;
  float s = 0.f, q = 0.f;
  for (int i = 0; i < 32; i++) { s += part[(b*32+i)*2]; q += part[(b*32+i)*2+1]; }
  const float inv = 1.f / (float)SD_;
  float mean = s * inv;
  float var = q * inv - mean * mean;
  float rs = rsqrtf(var + 1e-5f);
  size_t base = (size_t)b * SD_;
  #pragma unroll
  for (int i = 0; i < 8; i++) {
    int li4 = c*2048 + i*256 + tid;   // 4-elem index within slab
    u16x4 rv = ((const u16x4*)(r + base))[li4];
    f32x4 wv = ((const f32x4*)w)[li4];
    f32x4 bv = ((const f32x4*)bb)[li4];
    f32x4 ov;
    #pragma unroll
    for (int jj = 0; jj < 4; jj++) ov[jj] = (bf2f(rv[jj]) - mean) * rs * wv[jj] + bv[jj];
    if (WF) ((f32x4*)(outF + base))[li4] = ov;
    if (WB) {
      u16x4 ub = { f2bf(ov[0]), f2bf(ov[1]), f2bf(ov[2]), f2bf(ov[3]) };
      ((u16x4*)(outB + base))[li4] = ub;
    }
  }
}

// ---------------- launch ----------------
extern "C" void kernel_launch(void* const* d_in, const int* in_sizes, int n_in,
                              void* d_out, int out_size, void* d_ws, size_t ws_size,
                              hipStream_t stream) {
  (void)in_sizes; (void)n_in; (void)out_size; (void)ws_size;
  const float* x    = (const float*)d_in[0];
  const float* mask = (const float*)d_in[1];
  const float* wq = (const float*)d_in[2];
  const float* bq = (const float*)d_in[3];
  const float* wk = (const float*)d_in[4];
  const float* bk = (const float*)d_in[5];
  const float* wv = (const float*)d_in[6];
  const float* bv = (const float*)d_in[7];
  const float* wo = (const float*)d_in[8];
  const float* bo = (const float*)d_in[9];
  const float* w1 = (const float*)d_in[10];
  const float* b1 = (const float*)d_in[11];
  const float* w2 = (const float*)d_in[12];
  const float* b2 = (const float*)d_in[13];
  const float* ln1w = (const float*)d_in[14];
  const float* ln1b = (const float*)d_in[15];
  const float* ln2w = (const float*)d_in[16];
  const float* ln2b = (const float*)d_in[17];
  float* out = (float*)d_out;

  char* ws = (char*)d_ws;
  const size_t MB = 1ull << 20;
  u16*   xb    = (u16*)(ws + 0);
  u16*   Qb    = (u16*)(ws + 16*MB);
  u16*   Kb    = (u16*)(ws + 32*MB);
  u16*   Vb    = (u16*)(ws + 48*MB);
  u16*   ctxb  = (u16*)(ws + 64*MB);
  u16*   res1b = (u16*)(ws + 80*MB);
  u16*   out1b = (u16*)(ws + 0);        // reuse xb (xb fully consumed by O-proj residual read)
  u16*   ffn1  = (u16*)(ws + 16*MB);    // reuse Q/K/V/ctx (dead after O-proj)
  u16*   res2b = (u16*)(ws + 112*MB);
  float* part  = (float*)(ws + 144*MB);
  u16*   wqkvT = (u16*)(ws + 145*MB);   // [1536][512] bf16
  u16*   woT   = (u16*)(ws + 147*MB);
  u16*   w1T   = (u16*)(ws + 148*MB);
  u16*   w2T   = (u16*)(ws + 150*MB);

  // fused prep: cast x + all 6 weight transposes
  prep_kernel<<<11264, 256, 0, stream>>>(
      x, xb, wq, wk, wv, wo, w1, w2, wqkvT, woT, w1T, w2T);

  // fused QKV projection: 128^2 split kernel, grid 1536 (nx=12, ypg=16)
  gemm128_qkv_kernel<<<1536, 256, 0, stream>>>(
      xb, wqkvT, bq, bk, bv, Qb, Kb, Vb, 512, 12, 16);

  attn_kernel<<<512, 512, 0, stream>>>(Qb, Kb, Vb, mask, ctxb);

  // O-proj: 128^2, residual = xb (bf16), bf16 out + fused LN1 partials. grid 512
  gemm_kernel<1,false,true><<<512, 256, 0, stream>>>(
      ctxb, woT, bo, nullptr, xb, res1b, part, 512, 512, 4, 16);

  ln_apply_kernel<true,false><<<dim3(64,16), 256, 0, stream>>>(
      res1b, part, ln1w, ln1b, nullptr, out1b);

  // FFN1: 256^2 8-wave BK=32 + ReLU, grid 512 (nx=8, ypg=8) = 2 blocks/CU exact
  gemm256_kernel<true><<<512, 512, 0, stream>>>(
      out1b, w1T, b1, ffn1, 512, 2048, 8, 8);

  // FFN2: 128^2, residual = out1b (bf16), bf16 out + fused LN2 partials. grid 512
  gemm_kernel<1,false,true><<<512, 256, 0, stream>>>(
      ffn1, w2T, b2, nullptr, out1b, res2b, part, 2048, 512, 4, 16);

  ln_apply_kernel<false,true><<<dim3(64,16), 256, 0, stream>>>(
      res2b, part, ln2w, ln2b, out, nullptr);
}

// Round 19
// 230.520 us; speedup vs baseline: 1.0329x; 1.0329x over previous
//
#include <hip/hip_runtime.h>
#include <stdint.h>

#define B_   16
#define S_   1024
#define D_   512
#define H_   8
#define DH_  64
#define DFF_ 2048
#define M_   (B_*S_)     // 16384
#define SD_  (S_*D_)     // 524288
#define NT_  16          // S_/64 KV tiles

typedef unsigned short u16;
typedef unsigned int u32;
typedef __attribute__((ext_vector_type(2))) unsigned int u32x2;
typedef __attribute__((ext_vector_type(4))) unsigned short u16x4;
typedef __attribute__((ext_vector_type(8))) short bf16x8;
typedef __attribute__((ext_vector_type(4))) float f32x4;
typedef __attribute__((ext_vector_type(16))) float f32x16;

#define LOG2E 1.4426950408889634f

#if defined(__has_builtin)
#if __has_builtin(__builtin_amdgcn_permlane32_swap)
#define HAVE_PLS 1
#endif
#endif

__device__ __forceinline__ u16 f2bf(float f) {
  union { float f; uint32_t u; } x{f};
  uint32_t r = x.u + 0x7fffu + ((x.u >> 16) & 1u);
  return (u16)(r >> 16);
}

__device__ __forceinline__ float bf2f(u16 v) {
  union { uint32_t u; float f; } x{(uint32_t)v << 16};
  return x.f;
}

// pack hi16(a), hi16(b) -> dword (truncating bf16 pair) via v_perm_b32
__device__ __forceinline__ u32 pk2(float lo, float hi) {
  union { float f; u32 u; } a{lo}, b{hi};
  return __builtin_amdgcn_perm(b.u, a.u, 0x07060302u);
}

__device__ __forceinline__ float exp2fast(float x) {
#if __has_builtin(__builtin_amdgcn_exp2f)
  return __builtin_amdgcn_exp2f(x);
#else
  return exp2f(x);
#endif
}

__device__ __forceinline__ void gload16(const u16* g, u16* l) {
  __builtin_amdgcn_global_load_lds(
      (const __attribute__((address_space(1))) uint32_t*)g,
      (__attribute__((address_space(3))) uint32_t*)l, 16, 0, 0);
}

__device__ __forceinline__ int swz3(int r) { return (r & 7) ^ ((r >> 3) & 7); }

// ---------------- fused prep: cast x + all 6 weight transposes, one dispatch ----------------
__global__ __launch_bounds__(256) void prep_kernel(
    const float* __restrict__ x, u16* __restrict__ xb,
    const float* __restrict__ wq, const float* __restrict__ wk,
    const float* __restrict__ wv, const float* __restrict__ wo,
    const float* __restrict__ w1, const float* __restrict__ w2,
    u16* __restrict__ wqkvT, u16* __restrict__ woT,
    u16* __restrict__ w1T, u16* __restrict__ w2T) {
  int bid = blockIdx.x, tid = threadIdx.x;
  if (bid < 8192) {
    int i = bid * 256 + tid;
    f32x4 v = ((const f32x4*)x)[i];
    u16x4 o = { f2bf(v[0]), f2bf(v[1]), f2bf(v[2]), f2bf(v[3]) };
    ((u16x4*)xb)[i] = o;
    return;
  }
  bid -= 8192;
  const float* W; u16* WT; int K, N, bx, by;
  if (bid < 1024) {
    int which = bid >> 8;
    W  = (which == 0) ? wq : (which == 1) ? wk : (which == 2) ? wv : wo;
    WT = (which == 3) ? woT : (wqkvT + (size_t)which * 512 * 512);
    K = 512; N = 512;
    int r = bid & 255; bx = r & 15; by = r >> 4;
  } else if (bid < 2048) {
    int r = bid - 1024; W = w1; WT = w1T; K = 512; N = 2048;
    bx = r & 63; by = r >> 6;
  } else {
    int r = bid - 2048; W = w2; WT = w2T; K = 2048; N = 512;
    bx = r & 15; by = r >> 4;
  }
  __shared__ float t[32][33];
  int n0 = bx * 32, k0 = by * 32;
  int tx = tid & 31, ty = tid >> 5;
  #pragma unroll
  for (int i = 0; i < 4; i++)
    t[ty + 8*i][tx] = W[(size_t)(k0 + ty + 8*i) * N + n0 + tx];
  __syncthreads();
  #pragma unroll
  for (int i = 0; i < 4; i++)
    WT[(size_t)(n0 + ty + 8*i) * K + k0 + tx] = f2bf(t[tx][ty + 8*i]);
}

// ================= 128x128 GEMM, 1 barrier per K-tile, swizzled LDS =================
// LDS slot swizzle: data k-group kg of row r lives at slot kg ^ ((r>>1)&3).
// Staged via linear global_load_lds dest + inverse-swizzled global source column.
// MODE 0: bf16 out (+RELU). MODE 1: bf16 residual-sum out + fused LN partials.
template<int MODE, bool RELU, bool RESB>
__global__ __launch_bounds__(256) void gemm_kernel(
    const u16* __restrict__ A, const u16* __restrict__ WT,
    const float* __restrict__ bias0, const float* __restrict__ res,
    const u16* __restrict__ resB,
    u16* __restrict__ out0,
    float* __restrict__ partOut, int K, int N, int nx, int ypg) {
  __shared__ u16 lA[2][128 * 32];
  __shared__ u16 lB[2][128 * 32];
  __shared__ float lred[8];
  int tid = threadIdx.x;
  int lane = tid & 63, wid = tid >> 6;
  int wr = wid >> 1, wc = wid & 1;
  int lrow = lane & 15, kg = lane >> 4;

  int dd = blockIdx.x;
  int cc = dd & 7, jj = dd >> 3;
  int bx = jj % nx, by = cc * ypg + jj / nx;
  int m0 = by * 128, n0 = bx * 128;

  int r0 = tid >> 2;
  int c0s = ((tid & 3) ^ ((r0 >> 1) & 3)) * 8;   // inverse-swizzled source col
  const u16* agp = A  + (size_t)m0 * K;
  const u16* bgp = WT + (size_t)n0 * K;

  // loop-invariant swizzled fragment offsets
  int aoff[4], boff[4];
  #pragma unroll
  for (int mi = 0; mi < 4; mi++) {
    int row = wr*64 + mi*16 + lrow;
    aoff[mi] = row*32 + ((kg ^ ((row >> 1) & 3)) * 8);
  }
  #pragma unroll
  for (int ni = 0; ni < 4; ni++) {
    int row = wc*64 + ni*16 + lrow;
    boff[ni] = row*32 + ((kg ^ ((row >> 1) & 3)) * 8);
  }

  f32x4 z = {0.f, 0.f, 0.f, 0.f};
  f32x4 acc[4][4];
  #pragma unroll
  for (int mi = 0; mi < 4; mi++)
    #pragma unroll
    for (int ni = 0; ni < 4; ni++) acc[mi][ni] = z;

#define STAGE_G(buf, kt) do { \
    gload16(agp + (size_t)r0 * K + (kt) + c0s,        &lA[buf][tid * 8]); \
    gload16(agp + (size_t)(r0 + 64) * K + (kt) + c0s, &lA[buf][2048 + tid * 8]); \
    gload16(bgp + (size_t)r0 * K + (kt) + c0s,        &lB[buf][tid * 8]); \
    gload16(bgp + (size_t)(r0 + 64) * K + (kt) + c0s, &lB[buf][2048 + tid * 8]); \
  } while (0)

  STAGE_G(0, 0);

  int nk = K / 32;
  int cur = 0;
  for (int t = 0; t < nk; t++) {
    __syncthreads();
    if (t + 1 < nk) STAGE_G(cur ^ 1, (t + 1) * 32);
    bf16x8 af[4], bfv[4];
    #pragma unroll
    for (int mi = 0; mi < 4; mi++)
      af[mi] = *(const bf16x8*)&lA[cur][aoff[mi]];
    #pragma unroll
    for (int ni = 0; ni < 4; ni++)
      bfv[ni] = *(const bf16x8*)&lB[cur][boff[ni]];
    __builtin_amdgcn_s_setprio(1);
    #pragma unroll
    for (int mi = 0; mi < 4; mi++)
      #pragma unroll
      for (int ni = 0; ni < 4; ni++)
        acc[mi][ni] = __builtin_amdgcn_mfma_f32_16x16x32_bf16(af[mi], bfv[ni], acc[mi][ni], 0, 0, 0);
    __builtin_amdgcn_s_setprio(0);
    cur ^= 1;
  }
#undef STAGE_G

  float s_acc = 0.f, q_acc = 0.f;
  #pragma unroll
  for (int mi = 0; mi < 4; mi++)
    #pragma unroll
    for (int ni = 0; ni < 4; ni++) {
      int col = n0 + wc*64 + ni*16 + lrow;
      float bv = bias0[col];
      #pragma unroll
      for (int r = 0; r < 4; r++) {
        int row = m0 + wr*64 + mi*16 + kg*4 + r;
        float v = acc[mi][ni][r] + bv;
        if (RELU) v = fmaxf(v, 0.f);
        size_t off = (size_t)row * N + col;
        if (MODE == 1) {
          float rv = RESB ? bf2f(resB[off]) : res[off];
          float tv = v + rv;
          out0[off] = f2bf(tv);
          s_acc += tv;
          q_acc += tv * tv;
        } else {
          out0[off] = f2bf(v);
        }
      }
    }

  if (MODE == 1) {
    #pragma unroll
    for (int dsh = 1; dsh < 64; dsh <<= 1) {
      s_acc += __shfl_xor(s_acc, dsh);
      q_acc += __shfl_xor(q_acc, dsh);
    }
    if (lane == 0) { lred[wid*2] = s_acc; lred[wid*2+1] = q_acc; }
    __syncthreads();
    if (tid == 0) {
      int batch = by >> 3;
      int pidx = batch*32 + (by & 7)*nx + bx;
      partOut[pidx*2]   = lred[0]+lred[2]+lred[4]+lred[6];
      partOut[pidx*2+1] = lred[1]+lred[3]+lred[5]+lred[7];
    }
  }
}

// ================= 128x128 QKV GEMM (N=1536 split into Q/K/V, Q scaled), swizzled LDS =================
__global__ __launch_bounds__(256) void gemm128_qkv_kernel(
    const u16* __restrict__ A, const u16* __restrict__ WT,
    const float* __restrict__ bq, const float* __restrict__ bk,
    const float* __restrict__ bv,
    u16* __restrict__ Qb, u16* __restrict__ Kb, u16* __restrict__ Vb,
    int K, int nx, int ypg) {
  __shared__ u16 lA[2][128 * 32];
  __shared__ u16 lB[2][128 * 32];
  int tid = threadIdx.x;
  int lane = tid & 63, wid = tid >> 6;
  int wr = wid >> 1, wc = wid & 1;
  int lrow = lane & 15, kg = lane >> 4;

  int dd = blockIdx.x;
  int cc = dd & 7, jj = dd >> 3;
  int bx = jj % nx, by = cc * ypg + jj / nx;
  int m0 = by * 128, n0 = bx * 128;

  int r0 = tid >> 2;
  int c0s = ((tid & 3) ^ ((r0 >> 1) & 3)) * 8;
  const u16* agp = A  + (size_t)m0 * K;
  const u16* bgp = WT + (size_t)n0 * K;

  int aoff[4], boff[4];
  #pragma unroll
  for (int mi = 0; mi < 4; mi++) {
    int row = wr*64 + mi*16 + lrow;
    aoff[mi] = row*32 + ((kg ^ ((row >> 1) & 3)) * 8);
  }
  #pragma unroll
  for (int ni = 0; ni < 4; ni++) {
    int row = wc*64 + ni*16 + lrow;
    boff[ni] = row*32 + ((kg ^ ((row >> 1) & 3)) * 8);
  }

  f32x4 z = {0.f, 0.f, 0.f, 0.f};
  f32x4 acc[4][4];
  #pragma unroll
  for (int mi = 0; mi < 4; mi++)
    #pragma unroll
    for (int ni = 0; ni < 4; ni++) acc[mi][ni] = z;

#define STAGE_G(buf, kt) do { \
    gload16(agp + (size_t)r0 * K + (kt) + c0s,        &lA[buf][tid * 8]); \
    gload16(agp + (size_t)(r0 + 64) * K + (kt) + c0s, &lA[buf][2048 + tid * 8]); \
    gload16(bgp + (size_t)r0 * K + (kt) + c0s,        &lB[buf][tid * 8]); \
    gload16(bgp + (size_t)(r0 + 64) * K + (kt) + c0s, &lB[buf][2048 + tid * 8]); \
  } while (0)

  STAGE_G(0, 0);

  int nk = K / 32;
  int cur = 0;
  for (int t = 0; t < nk; t++) {
    __syncthreads();
    if (t + 1 < nk) STAGE_G(cur ^ 1, (t + 1) * 32);
    bf16x8 af[4], bfv[4];
    #pragma unroll
    for (int mi = 0; mi < 4; mi++)
      af[mi] = *(const bf16x8*)&lA[cur][aoff[mi]];
    #pragma unroll
    for (int ni = 0; ni < 4; ni++)
      bfv[ni] = *(const bf16x8*)&lB[cur][boff[ni]];
    __builtin_amdgcn_s_setprio(1);
    #pragma unroll
    for (int mi = 0; mi < 4; mi++)
      #pragma unroll
      for (int ni = 0; ni < 4; ni++)
        acc[mi][ni] = __builtin_amdgcn_mfma_f32_16x16x32_bf16(af[mi], bfv[ni], acc[mi][ni], 0, 0, 0);
    __builtin_amdgcn_s_setprio(0);
    cur ^= 1;
  }
#undef STAGE_G

  int seg = n0 >> 9;                       // 0=Q, 1=K, 2=V
  const float* bp = (seg == 0) ? bq : (seg == 1) ? bk : bv;
  u16* op = (seg == 0) ? Qb : (seg == 1) ? Kb : Vb;
  float aeff = (seg == 0) ? 0.125f * LOG2E : 1.0f;

  #pragma unroll
  for (int mi = 0; mi < 4; mi++)
    #pragma unroll
    for (int ni = 0; ni < 4; ni++) {
      int col = n0 + wc*64 + ni*16 + lrow;
      int ocol = col & 511;
      float bvv = bp[ocol];
      #pragma unroll
      for (int r = 0; r < 4; r++) {
        int row = m0 + wr*64 + mi*16 + kg*4 + r;
        float v = (acc[mi][ni][r] + bvv) * aeff;
        op[(size_t)row * 512 + ocol] = f2bf(v);
      }
    }
}

// ---------------- flash attention v11: 8-wave blocks, 256 q-rows, shared K/V staging ----------------
// grid 512; waves 0-3 stage V (reg->LDS transpose), waves 4-7 stage K (global_load_lds DMA).
__global__ __launch_bounds__(512) void attn_kernel(
    const u16* __restrict__ Q, const u16* __restrict__ Km,
    const u16* __restrict__ Vm, const float* __restrict__ mask,
    u16* __restrict__ ctx) {
  __shared__ u16 lK[2][4096];     // [key 64][dh 64], dword-swizzled, 128B rows
  __shared__ u16 lV[2][4096];     // [dh 64][key 64] transposed, dword-swizzled
  __shared__ float lBias[1024];
  int tid = threadIdx.x, lane = tid & 63, wid = tid >> 6;   // wid 0..7
  int la = lane & 31, hi = lane >> 5;
  int wg = blockIdx.x;
  int xcd = wg & 7, idx = wg >> 3;      // idx 0..63
  int bh = xcd * 16 + (idx & 15);
  int qt = idx >> 4;                    // 0..3 (256-row q tiles)
  int b = bh >> 3, h = bh & 7;
  bool vwave = (wid < 4);               // wave-uniform staging split
  int tid2 = tid & 255;                 // K-staging index for waves 4-7

  const u16* qp = Q + (size_t)(b*S_ + qt*256 + wid*32 + la) * D_ + h*DH_ + hi*8;
  bf16x8 qf[4];
  #pragma unroll
  for (int c = 0; c < 4; c++) qf[c] = *(const bf16x8*)(qp + c*16);

  int krow = tid2 >> 3;                 // 0..31 (K rows, +32 second call)
  int kcol = 8 * (tid2 & 7);
  int kc0 = kcol ^ (swz3(krow) << 3);
  int kc1 = kcol ^ (swz3(krow + 32) << 3);
  int va = tid & 7, vp = (tid >> 3) & 31;   // V staging map (waves 0-3: tid<256)
  const u16* kbase = Km + ((size_t)b*S_) * D_ + h*DH_;
  const u16* vbase = Vm + ((size_t)b*S_) * D_ + h*DH_ + 8*va;

#define STAGE_K(buf, tt) do { \
    const u16* kt_ = kbase + (size_t)(tt)*64*D_; \
    gload16(kt_ + (size_t)krow*D_ + kc0,        &lK[buf][tid2*8]); \
    gload16(kt_ + (size_t)(krow+32)*D_ + kc1,   &lK[buf][2048 + tid2*8]); \
  } while (0)
#define LOAD_V(tt) do { \
    const u16* vt_ = vbase + (size_t)((tt)*64 + 2*vp) * D_; \
    nv0 = *(const bf16x8*)vt_; nv1 = *(const bf16x8*)(vt_ + D_); \
  } while (0)
#define WRITE_V(buf) do { \
    u32* lVd_ = (u32*)lV[buf]; \
    _Pragma("unroll") \
    for (int jv = 0; jv < 8; jv++) { \
      int row_ = 8*va + jv; \
      u32 pv_ = (u32)(u16)nv0[jv] | ((u32)(u16)nv1[jv] << 16); \
      lVd_[row_*32 + (vp ^ (swz3(row_) << 2))] = pv_; \
    } \
  } while (0)

  int swk0 = swz3(la) << 2, swk1 = swz3(la + 32) << 2;
  f32x16 oc0, oc1;
  #pragma unroll
  for (int i = 0; i < 16; i++) { oc0[i] = 0.f; oc1[i] = 0.f; }
  float lsum = 0.f;

#define QKT(d0, d1, tt) do { \
    _Pragma("unroll") \
    for (int rq = 0; rq < 4; rq++) { \
      f32x4 bb0 = *(const f32x4*)&lBias[(tt)*64 + rq*8 + hi*4]; \
      f32x4 bb1 = *(const f32x4*)&lBias[(tt)*64 + 32 + rq*8 + hi*4]; \
      _Pragma("unroll") \
      for (int jj = 0; jj < 4; jj++) { d0[rq*4+jj] = bb0[jj]; d1[rq*4+jj] = bb1[jj]; } \
    } \
    { const u16* lkb_ = lK[(tt)&1]; \
      __builtin_amdgcn_s_setprio(1); \
      _Pragma("unroll") \
      for (int c_ = 0; c_ < 4; c_++) { \
        int dwb_ = c_*8 + hi*4; \
        bf16x8 kf0_ = *(const bf16x8*)&lkb_[la*64 + ((dwb_ ^ swk0) << 1)]; \
        bf16x8 kf1_ = *(const bf16x8*)&lkb_[(la+32)*64 + ((dwb_ ^ swk1) << 1)]; \
        d0 = __builtin_amdgcn_mfma_f32_32x32x16_bf16(kf0_, qf[c_], d0, 0, 0, 0); \
        d1 = __builtin_amdgcn_mfma_f32_32x32x16_bf16(kf1_, qf[c_], d1, 0, 0, 0); \
      } \
      __builtin_amdgcn_s_setprio(0); } \
  } while (0)

#define SOFTPV(s0v, s1v, tt) do { \
    float rsp_[4] = {0.f, 0.f, 0.f, 0.f}; \
    _Pragma("unroll") \
    for (int i_ = 0; i_ < 16; i_++) { float e_ = exp2fast(s0v[i_]); s0v[i_] = e_; rsp_[i_ & 3] += e_; } \
    _Pragma("unroll") \
    for (int i_ = 0; i_ < 16; i_++) { float e_ = exp2fast(s1v[i_]); s1v[i_] = e_; rsp_[i_ & 3] += e_; } \
    lsum += (rsp_[0] + rsp_[1]) + (rsp_[2] + rsp_[3]); \
    { const u16* lvb_ = lV[(tt)&1]; \
      __builtin_amdgcn_s_setprio(1); \
      _Pragma("unroll") \
      for (int cc_ = 0; cc_ < 4; cc_++) { \
        const int base_ = 8 * (cc_ & 1); \
        float pv_[8]; \
        _Pragma("unroll") \
        for (int k_ = 0; k_ < 8; k_++) pv_[k_] = (cc_ < 2) ? s0v[base_ + k_] : s1v[base_ + k_]; \
        u32 a0_ = pk2(pv_[0], pv_[1]); \
        u32 a1_ = pk2(pv_[2], pv_[3]); \
        u32 b0_ = pk2(pv_[4], pv_[5]); \
        u32 b1_ = pk2(pv_[6], pv_[7]); \
        union { u32 u[4]; bf16x8 v; } pf_; \
        PEXCH(pf_, a0_, a1_, b0_, b1_); \
        _Pragma("unroll") \
        for (int vb_ = 0; vb_ < 2; vb_++) { \
          int row_ = vb_*32 + la; \
          int dwv_ = (cc_*8 + hi*4) ^ (swz3(row_) << 2); \
          bf16x8 vf_ = *(const bf16x8*)&lvb_[row_*64 + (dwv_ << 1)]; \
          if (vb_ == 0) oc0 = __builtin_amdgcn_mfma_f32_32x32x16_bf16(pf_.v, vf_, oc0, 0, 0, 0); \
          else          oc1 = __builtin_amdgcn_mfma_f32_32x32x16_bf16(pf_.v, vf_, oc1, 0, 0, 0); \
        } \
      } \
      __builtin_amdgcn_s_setprio(0); } \
  } while (0)

#ifdef HAVE_PLS
#define PEXCH(pf_, a0_, a1_, b0_, b1_) do { \
    u32x2 r0_ = __builtin_amdgcn_permlane32_swap(a0_, b0_, false, false); \
    u32x2 r1_ = __builtin_amdgcn_permlane32_swap(a1_, b1_, false, false); \
    pf_.u[0] = r0_[0]; pf_.u[1] = r1_[0]; pf_.u[2] = r0_[1]; pf_.u[3] = r1_[1]; \
  } while (0)
#else
#define PEXCH(pf_, a0_, a1_, b0_, b1_) do { \
    u32 sd0_ = hi ? a0_ : b0_, sd1_ = hi ? a1_ : b1_; \
    u32 x0_ = (u32)__shfl_xor((int)sd0_, 32); \
    u32 x1_ = (u32)__shfl_xor((int)sd1_, 32); \
    pf_.u[0] = hi ? x0_ : a0_; \
    pf_.u[1] = hi ? x1_ : a1_; \
    pf_.u[2] = hi ? b0_ : x0_; \
    pf_.u[3] = hi ? b1_ : x1_; \
  } while (0)
#endif

  // ---- prologue: waves 0-3 stage V0 + bias, load V1; waves 4-7 DMA K0,K1 ----
  bf16x8 nv0, nv1;
  if (vwave) {
    f32x4 mv = ((const f32x4*)(mask + (size_t)b*S_))[tid];
    f32x4 bv;
    #pragma unroll
    for (int jj = 0; jj < 4; jj++) bv[jj] = mv[jj] * (-1.0e9f * LOG2E);
    ((f32x4*)lBias)[tid] = bv;
    LOAD_V(0);
    WRITE_V(0);
    LOAD_V(1);
  } else {
    STAGE_K(0, 0);
    STAGE_K(1, 1);
  }
  __syncthreads();

  f32x16 sA0, sA1, sB0, sB1;
  QKT(sA0, sA1, 0);
  __syncthreads();          // all waves done reading lK[0] before iter0 re-DMAs it

  // ---- pipelined main loop, unrolled by 2 (A/B score states) ----
  for (int t = 0; t < NT_; t += 2) {
    if (!vwave) { if (t + 2 < NT_) STAGE_K(t & 1, t + 2); }
    if (vwave) {
      WRITE_V((t + 1) & 1);
      if (t + 2 < NT_) LOAD_V(t + 2);
    }
    QKT(sB0, sB1, t + 1);
    SOFTPV(sA0, sA1, t);
    __syncthreads();
    {
      int u = t + 1;
      if (!vwave) { if (u + 2 < NT_) STAGE_K(u & 1, u + 2); }
      if (vwave) {
        if (u + 1 < NT_) WRITE_V((u + 1) & 1);
        if (u + 2 < NT_) LOAD_V(u + 2);
      }
      if (u + 1 < NT_) QKT(sA0, sA1, u + 1);
      SOFTPV(sB0, sB1, u);
      __syncthreads();
    }
  }
#undef STAGE_K
#undef LOAD_V
#undef WRITE_V
#undef QKT
#undef SOFTPV
#undef PEXCH

  // ---- epilogue ----
  lsum += __shfl_xor(lsum, 32);
  float linv = 1.f / lsum;
  #pragma unroll
  for (int r = 0; r < 16; r++) {
    int qr = (r&3) + 8*(r>>2) + 4*hi;
    float lr = __shfl(linv, qr);
    size_t rowoff = (size_t)(b*S_ + qt*256 + wid*32 + qr) * D_ + h*DH_;
    ctx[rowoff + la]      = f2bf(oc0[r] * lr);
    ctx[rowoff + 32 + la] = f2bf(oc1[r] * lr);
  }
}

// ---------------- LayerNorm apply (bf16 input; partials from GEMM epilogue) ----------------
template<bool WB, bool WF>
__global__ __launch_bounds__(256) void ln_apply_kernel(
    const u16* __restrict__ r, const float* __restrict__ part,
    const float* __restrict__ w, const float* __restrict__ bb,
    float* __restrict__ outF, u16* __restrict__ outB) {
  int b = blockIdx.y, c = blockIdx.x, tid = threadIdx.x;
  float s = 0.f, q = 0.f;
  for (int i = 0; i < 32; i++) { s += part[(b*32+i)*2]; q += part[(b*32+i)*2+1]; }
  const float inv = 1.f / (float)SD_;
  float mean = s * inv;
  float var = q * inv - mean * mean;
  float rs = rsqrtf(var + 1e-5f);
  size_t base = (size_t)b * SD_;
  #pragma unroll
  for (int i = 0; i < 8; i++) {
    int li4 = c*2048 + i*256 + tid;   // 4-elem index within slab
    u16x4 rv = ((const u16x4*)(r + base))[li4];
    f32x4 wv = ((const f32x4*)w)[li4];
    f32x4 bv = ((const f32x4*)bb)[li4];
    f32x4 ov;
    #pragma unroll
    for (int jj = 0; jj < 4; jj++) ov[jj] = (bf2f(rv[jj]) - mean) * rs * wv[jj] + bv[jj];
    if (WF) ((f32x4*)(outF + base))[li4] = ov;
    if (WB) {
      u16x4 ub = { f2bf(ov[0]), f2bf(ov[1]), f2bf(ov[2]), f2bf(ov[3]) };
      ((u16x4*)(outB + base))[li4] = ub;
    }
  }
}

// ---------------- launch ----------------
extern "C" void kernel_launch(void* const* d_in, const int* in_sizes, int n_in,
                              void* d_out, int out_size, void* d_ws, size_t ws_size,
                              hipStream_t stream) {
  (void)in_sizes; (void)n_in; (void)out_size; (void)ws_size;
  const float* x    = (const float*)d_in[0];
  const float* mask = (const float*)d_in[1];
  const float* wq = (const float*)d_in[2];
  const float* bq = (const float*)d_in[3];
  const float* wk = (const float*)d_in[4];
  const float* bk = (const float*)d_in[5];
  const float* wv = (const float*)d_in[6];
  const float* bv = (const float*)d_in[7];
  const float* wo = (const float*)d_in[8];
  const float* bo = (const float*)d_in[9];
  const float* w1 = (const float*)d_in[10];
  const float* b1 = (const float*)d_in[11];
  const float* w2 = (const float*)d_in[12];
  const float* b2 = (const float*)d_in[13];
  const float* ln1w = (const float*)d_in[14];
  const float* ln1b = (const float*)d_in[15];
  const float* ln2w = (const float*)d_in[16];
  const float* ln2b = (const float*)d_in[17];
  float* out = (float*)d_out;

  char* ws = (char*)d_ws;
  const size_t MB = 1ull << 20;
  u16*   xb    = (u16*)(ws + 0);
  u16*   Qb    = (u16*)(ws + 16*MB);
  u16*   Kb    = (u16*)(ws + 32*MB);
  u16*   Vb    = (u16*)(ws + 48*MB);
  u16*   ctxb  = (u16*)(ws + 64*MB);
  u16*   res1b = (u16*)(ws + 80*MB);
  u16*   out1b = (u16*)(ws + 0);        // reuse xb (xb fully consumed by O-proj residual read)
  u16*   ffn1  = (u16*)(ws + 16*MB);    // reuse Q/K/V/ctx (dead after O-proj)
  u16*   res2b = (u16*)(ws + 112*MB);
  float* part  = (float*)(ws + 144*MB);
  u16*   wqkvT = (u16*)(ws + 145*MB);   // [1536][512] bf16
  u16*   woT   = (u16*)(ws + 147*MB);
  u16*   w1T   = (u16*)(ws + 148*MB);
  u16*   w2T   = (u16*)(ws + 150*MB);

  // fused prep: cast x + all 6 weight transposes
  prep_kernel<<<11264, 256, 0, stream>>>(
      x, xb, wq, wk, wv, wo, w1, w2, wqkvT, woT, w1T, w2T);

  // fused QKV projection: 128^2 split kernel, grid 1536 (nx=12, ypg=16)
  gemm128_qkv_kernel<<<1536, 256, 0, stream>>>(
      xb, wqkvT, bq, bk, bv, Qb, Kb, Vb, 512, 12, 16);

  attn_kernel<<<512, 512, 0, stream>>>(Qb, Kb, Vb, mask, ctxb);

  // O-proj: 128^2, residual = xb (bf16), bf16 out + fused LN1 partials. grid 512
  gemm_kernel<1,false,true><<<512, 256, 0, stream>>>(
      ctxb, woT, bo, nullptr, xb, res1b, part, 512, 512, 4, 16);

  ln_apply_kernel<true,false><<<dim3(64,16), 256, 0, stream>>>(
      res1b, part, ln1w, ln1b, nullptr, out1b);

  // FFN1: 128^2 + ReLU, grid 2048 (nx=16, ypg=16)
  gemm_kernel<0,true,false><<<2048, 256, 0, stream>>>(
      out1b, w1T, b1, nullptr, nullptr, ffn1, nullptr, 512, 2048, 16, 16);

  // FFN2: 128^2, residual = out1b (bf16), bf16 out + fused LN2 partials. grid 512
  gemm_kernel<1,false,true><<<512, 256, 0, stream>>>(
      ffn1, w2T, b2, nullptr, out1b, res2b, part, 2048, 512, 4, 16);

  ln_apply_kernel<false,true><<<dim3(64,16), 256, 0, stream>>>(
      res2b, part, ln2w, ln2b, out, nullptr);
}

// Round 20
// 226.831 us; speedup vs baseline: 1.0497x; 1.0163x over previous
//
#include <hip/hip_runtime.h>
#include <stdint.h>

#define B_   16
#define S_   1024
#define D_   512
#define H_   8
#define DH_  64
#define DFF_ 2048
#define M_   (B_*S_)     // 16384
#define SD_  (S_*D_)     // 524288
#define NT_  16          // S_/64 KV tiles

typedef unsigned short u16;
typedef unsigned int u32;
typedef __attribute__((ext_vector_type(2))) unsigned int u32x2;
typedef __attribute__((ext_vector_type(4))) unsigned short u16x4;
typedef __attribute__((ext_vector_type(8))) short bf16x8;
typedef __attribute__((ext_vector_type(4))) float f32x4;
typedef __attribute__((ext_vector_type(16))) float f32x16;

#define LOG2E 1.4426950408889634f

#if defined(__has_builtin)
#if __has_builtin(__builtin_amdgcn_permlane32_swap)
#define HAVE_PLS 1
#endif
#endif

__device__ __forceinline__ u16 f2bf(float f) {
  union { float f; uint32_t u; } x{f};
  uint32_t r = x.u + 0x7fffu + ((x.u >> 16) & 1u);
  return (u16)(r >> 16);
}

__device__ __forceinline__ float bf2f(u16 v) {
  union { uint32_t u; float f; } x{(uint32_t)v << 16};
  return x.f;
}

// pack hi16(a), hi16(b) -> dword (truncating bf16 pair) via v_perm_b32
__device__ __forceinline__ u32 pk2(float lo, float hi) {
  union { float f; u32 u; } a{lo}, b{hi};
  return __builtin_amdgcn_perm(b.u, a.u, 0x07060302u);
}

__device__ __forceinline__ float exp2fast(float x) {
#if __has_builtin(__builtin_amdgcn_exp2f)
  return __builtin_amdgcn_exp2f(x);
#else
  return exp2f(x);
#endif
}

__device__ __forceinline__ void gload16(const u16* g, u16* l) {
  __builtin_amdgcn_global_load_lds(
      (const __attribute__((address_space(1))) uint32_t*)g,
      (__attribute__((address_space(3))) uint32_t*)l, 16, 0, 0);
}

__device__ __forceinline__ int swz3(int r) { return (r & 7) ^ ((r >> 3) & 7); }

// ---------------- fused prep: cast x + all 6 weight transposes, one dispatch ----------------
__global__ __launch_bounds__(256) void prep_kernel(
    const float* __restrict__ x, u16* __restrict__ xb,
    const float* __restrict__ wq, const float* __restrict__ wk,
    const float* __restrict__ wv, const float* __restrict__ wo,
    const float* __restrict__ w1, const float* __restrict__ w2,
    u16* __restrict__ wqkvT, u16* __restrict__ woT,
    u16* __restrict__ w1T, u16* __restrict__ w2T) {
  int bid = blockIdx.x, tid = threadIdx.x;
  if (bid < 8192) {
    int i = bid * 256 + tid;
    f32x4 v = ((const f32x4*)x)[i];
    u16x4 o = { f2bf(v[0]), f2bf(v[1]), f2bf(v[2]), f2bf(v[3]) };
    ((u16x4*)xb)[i] = o;
    return;
  }
  bid -= 8192;
  const float* W; u16* WT; int K, N, bx, by;
  if (bid < 1024) {
    int which = bid >> 8;
    W  = (which == 0) ? wq : (which == 1) ? wk : (which == 2) ? wv : wo;
    WT = (which == 3) ? woT : (wqkvT + (size_t)which * 512 * 512);
    K = 512; N = 512;
    int r = bid & 255; bx = r & 15; by = r >> 4;
  } else if (bid < 2048) {
    int r = bid - 1024; W = w1; WT = w1T; K = 512; N = 2048;
    bx = r & 63; by = r >> 6;
  } else {
    int r = bid - 2048; W = w2; WT = w2T; K = 2048; N = 512;
    bx = r & 15; by = r >> 4;
  }
  __shared__ float t[32][33];
  int n0 = bx * 32, k0 = by * 32;
  int tx = tid & 31, ty = tid >> 5;
  #pragma unroll
  for (int i = 0; i < 4; i++)
    t[ty + 8*i][tx] = W[(size_t)(k0 + ty + 8*i) * N + n0 + tx];
  __syncthreads();
  #pragma unroll
  for (int i = 0; i < 4; i++)
    WT[(size_t)(n0 + ty + 8*i) * K + k0 + tx] = f2bf(t[tx][ty + 8*i]);
}

// ================= 128x128 GEMM, 1 barrier per K-tile, swizzled LDS =================
// MODE 0: bf16 out (+RELU). MODE 1: bf16 residual-sum out + fused LN partials.
template<int MODE, bool RELU, bool RESB>
__global__ __launch_bounds__(256) void gemm_kernel(
    const u16* __restrict__ A, const u16* __restrict__ WT,
    const float* __restrict__ bias0, const float* __restrict__ res,
    const u16* __restrict__ resB,
    u16* __restrict__ out0,
    float* __restrict__ partOut, int K, int N, int nx, int ypg) {
  __shared__ u16 lA[2][128 * 32];
  __shared__ u16 lB[2][128 * 32];
  __shared__ float lred[8];
  int tid = threadIdx.x;
  int lane = tid & 63, wid = tid >> 6;
  int wr = wid >> 1, wc = wid & 1;
  int lrow = lane & 15, kg = lane >> 4;

  int dd = blockIdx.x;
  int cc = dd & 7, jj = dd >> 3;
  int bx = jj % nx, by = cc * ypg + jj / nx;
  int m0 = by * 128, n0 = bx * 128;

  int r0 = tid >> 2;
  int c0s = ((tid & 3) ^ ((r0 >> 1) & 3)) * 8;   // inverse-swizzled source col
  const u16* agp = A  + (size_t)m0 * K;
  const u16* bgp = WT + (size_t)n0 * K;

  int aoff[4], boff[4];
  #pragma unroll
  for (int mi = 0; mi < 4; mi++) {
    int row = wr*64 + mi*16 + lrow;
    aoff[mi] = row*32 + ((kg ^ ((row >> 1) & 3)) * 8);
  }
  #pragma unroll
  for (int ni = 0; ni < 4; ni++) {
    int row = wc*64 + ni*16 + lrow;
    boff[ni] = row*32 + ((kg ^ ((row >> 1) & 3)) * 8);
  }

  f32x4 z = {0.f, 0.f, 0.f, 0.f};
  f32x4 acc[4][4];
  #pragma unroll
  for (int mi = 0; mi < 4; mi++)
    #pragma unroll
    for (int ni = 0; ni < 4; ni++) acc[mi][ni] = z;

#define STAGE_G(buf, kt) do { \
    gload16(agp + (size_t)r0 * K + (kt) + c0s,        &lA[buf][tid * 8]); \
    gload16(agp + (size_t)(r0 + 64) * K + (kt) + c0s, &lA[buf][2048 + tid * 8]); \
    gload16(bgp + (size_t)r0 * K + (kt) + c0s,        &lB[buf][tid * 8]); \
    gload16(bgp + (size_t)(r0 + 64) * K + (kt) + c0s, &lB[buf][2048 + tid * 8]); \
  } while (0)

  STAGE_G(0, 0);

  int nk = K / 32;
  int cur = 0;
  for (int t = 0; t < nk; t++) {
    __syncthreads();
    if (t + 1 < nk) STAGE_G(cur ^ 1, (t + 1) * 32);
    bf16x8 af[4], bfv[4];
    #pragma unroll
    for (int mi = 0; mi < 4; mi++)
      af[mi] = *(const bf16x8*)&lA[cur][aoff[mi]];
    #pragma unroll
    for (int ni = 0; ni < 4; ni++)
      bfv[ni] = *(const bf16x8*)&lB[cur][boff[ni]];
    __builtin_amdgcn_s_setprio(1);
    #pragma unroll
    for (int mi = 0; mi < 4; mi++)
      #pragma unroll
      for (int ni = 0; ni < 4; ni++)
        acc[mi][ni] = __builtin_amdgcn_mfma_f32_16x16x32_bf16(af[mi], bfv[ni], acc[mi][ni], 0, 0, 0);
    __builtin_amdgcn_s_setprio(0);
    cur ^= 1;
  }
#undef STAGE_G

  float s_acc = 0.f, q_acc = 0.f;
  #pragma unroll
  for (int mi = 0; mi < 4; mi++)
    #pragma unroll
    for (int ni = 0; ni < 4; ni++) {
      int col = n0 + wc*64 + ni*16 + lrow;
      float bv = bias0[col];
      #pragma unroll
      for (int r = 0; r < 4; r++) {
        int row = m0 + wr*64 + mi*16 + kg*4 + r;
        float v = acc[mi][ni][r] + bv;
        if (RELU) v = fmaxf(v, 0.f);
        size_t off = (size_t)row * N + col;
        if (MODE == 1) {
          float rv = RESB ? bf2f(resB[off]) : res[off];
          float tv = v + rv;
          out0[off] = f2bf(tv);
          s_acc += tv;
          q_acc += tv * tv;
        } else {
          out0[off] = f2bf(v);
        }
      }
    }

  if (MODE == 1) {
    #pragma unroll
    for (int dsh = 1; dsh < 64; dsh <<= 1) {
      s_acc += __shfl_xor(s_acc, dsh);
      q_acc += __shfl_xor(q_acc, dsh);
    }
    if (lane == 0) { lred[wid*2] = s_acc; lred[wid*2+1] = q_acc; }
    __syncthreads();
    if (tid == 0) {
      int batch = by >> 3;
      int pidx = batch*32 + (by & 7)*nx + bx;
      partOut[pidx*2]   = lred[0]+lred[2]+lred[4]+lred[6];
      partOut[pidx*2+1] = lred[1]+lred[3]+lred[5]+lred[7];
    }
  }
}

// ================= 128x256 8-wave GEMM (FFN1): same per-wave body, 2x barrier amortization =================
// 8 waves = 2M x 4N; per wave acc[4][4] (64 VGPR) identical to 128^2 kernel.
// LDS 48 KB -> 2 blocks/CU (VGPR-capped 4 waves/SIMD). Swizzle identical (row>>1 invariant).
template<bool RELU>
__global__ __launch_bounds__(512, 4) void gemm128x256_kernel(
    const u16* __restrict__ A, const u16* __restrict__ WT,
    const float* __restrict__ bias0,
    u16* __restrict__ out0, int K, int N, int nx, int ypg) {
  __shared__ u16 lA[2][128 * 32];   // 16 KB
  __shared__ u16 lB[2][256 * 32];   // 32 KB
  int tid = threadIdx.x;
  int lane = tid & 63, wid = tid >> 6;
  int wr = wid >> 2, wc = wid & 3;          // 2M x 4N waves
  int lrow = lane & 15, kg = lane >> 4;

  int dd = blockIdx.x;
  int cc = dd & 7, jj = dd >> 3;
  int bx = jj % nx, by = cc * ypg + jj / nx;
  int m0 = by * 128, n0 = bx * 256;

  int r0 = tid >> 2;                               // 0..127
  int c0s = ((tid & 3) ^ ((r0 >> 1) & 3)) * 8;     // inverse-swizzled source col (+128 invariant)
  const u16* agp = A  + (size_t)m0 * K;
  const u16* bgp = WT + (size_t)n0 * K;

  int aoff[4], boff[4];
  #pragma unroll
  for (int mi = 0; mi < 4; mi++) {
    int row = wr*64 + mi*16 + lrow;
    aoff[mi] = row*32 + ((kg ^ ((row >> 1) & 3)) * 8);
  }
  #pragma unroll
  for (int ni = 0; ni < 4; ni++) {
    int row = wc*64 + ni*16 + lrow;                // 0..255
    boff[ni] = row*32 + ((kg ^ ((row >> 1) & 3)) * 8);
  }

  f32x4 z = {0.f, 0.f, 0.f, 0.f};
  f32x4 acc[4][4];
  #pragma unroll
  for (int mi = 0; mi < 4; mi++)
    #pragma unroll
    for (int ni = 0; ni < 4; ni++) acc[mi][ni] = z;

#define STG(buf, kt) do { \
    gload16(agp + (size_t)r0 * K + (kt) + c0s,         &lA[buf][tid * 8]); \
    gload16(bgp + (size_t)r0 * K + (kt) + c0s,         &lB[buf][tid * 8]); \
    gload16(bgp + (size_t)(r0 + 128) * K + (kt) + c0s, &lB[buf][4096 + tid * 8]); \
  } while (0)

  STG(0, 0);

  int nk = K / 32;
  int cur = 0;
  for (int t = 0; t < nk; t++) {
    __syncthreads();                 // single sync point per tile
    if (t + 1 < nk) STG(cur ^ 1, (t + 1) * 32);
    bf16x8 af[4], bfv[4];
    #pragma unroll
    for (int mi = 0; mi < 4; mi++)
      af[mi] = *(const bf16x8*)&lA[cur][aoff[mi]];
    #pragma unroll
    for (int ni = 0; ni < 4; ni++)
      bfv[ni] = *(const bf16x8*)&lB[cur][boff[ni]];
    __builtin_amdgcn_s_setprio(1);
    #pragma unroll
    for (int mi = 0; mi < 4; mi++)
      #pragma unroll
      for (int ni = 0; ni < 4; ni++)
        acc[mi][ni] = __builtin_amdgcn_mfma_f32_16x16x32_bf16(af[mi], bfv[ni], acc[mi][ni], 0, 0, 0);
    __builtin_amdgcn_s_setprio(0);
    cur ^= 1;
  }
#undef STG

  #pragma unroll
  for (int mi = 0; mi < 4; mi++)
    #pragma unroll
    for (int ni = 0; ni < 4; ni++) {
      int col = n0 + wc*64 + ni*16 + lrow;
      float bv = bias0[col];
      #pragma unroll
      for (int r = 0; r < 4; r++) {
        int row = m0 + wr*64 + mi*16 + kg*4 + r;
        float v = acc[mi][ni][r] + bv;
        if (RELU) v = fmaxf(v, 0.f);
        out0[(size_t)row * N + col] = f2bf(v);
      }
    }
}

// ================= 128x128 QKV GEMM (N=1536 split into Q/K/V, Q scaled), swizzled LDS =================
__global__ __launch_bounds__(256) void gemm128_qkv_kernel(
    const u16* __restrict__ A, const u16* __restrict__ WT,
    const float* __restrict__ bq, const float* __restrict__ bk,
    const float* __restrict__ bv,
    u16* __restrict__ Qb, u16* __restrict__ Kb, u16* __restrict__ Vb,
    int K, int nx, int ypg) {
  __shared__ u16 lA[2][128 * 32];
  __shared__ u16 lB[2][128 * 32];
  int tid = threadIdx.x;
  int lane = tid & 63, wid = tid >> 6;
  int wr = wid >> 1, wc = wid & 1;
  int lrow = lane & 15, kg = lane >> 4;

  int dd = blockIdx.x;
  int cc = dd & 7, jj = dd >> 3;
  int bx = jj % nx, by = cc * ypg + jj / nx;
  int m0 = by * 128, n0 = bx * 128;

  int r0 = tid >> 2;
  int c0s = ((tid & 3) ^ ((r0 >> 1) & 3)) * 8;
  const u16* agp = A  + (size_t)m0 * K;
  const u16* bgp = WT + (size_t)n0 * K;

  int aoff[4], boff[4];
  #pragma unroll
  for (int mi = 0; mi < 4; mi++) {
    int row = wr*64 + mi*16 + lrow;
    aoff[mi] = row*32 + ((kg ^ ((row >> 1) & 3)) * 8);
  }
  #pragma unroll
  for (int ni = 0; ni < 4; ni++) {
    int row = wc*64 + ni*16 + lrow;
    boff[ni] = row*32 + ((kg ^ ((row >> 1) & 3)) * 8);
  }

  f32x4 z = {0.f, 0.f, 0.f, 0.f};
  f32x4 acc[4][4];
  #pragma unroll
  for (int mi = 0; mi < 4; mi++)
    #pragma unroll
    for (int ni = 0; ni < 4; ni++) acc[mi][ni] = z;

#define STAGE_G(buf, kt) do { \
    gload16(agp + (size_t)r0 * K + (kt) + c0s,        &lA[buf][tid * 8]); \
    gload16(agp + (size_t)(r0 + 64) * K + (kt) + c0s, &lA[buf][2048 + tid * 8]); \
    gload16(bgp + (size_t)r0 * K + (kt) + c0s,        &lB[buf][tid * 8]); \
    gload16(bgp + (size_t)(r0 + 64) * K + (kt) + c0s, &lB[buf][2048 + tid * 8]); \
  } while (0)

  STAGE_G(0, 0);

  int nk = K / 32;
  int cur = 0;
  for (int t = 0; t < nk; t++) {
    __syncthreads();
    if (t + 1 < nk) STAGE_G(cur ^ 1, (t + 1) * 32);
    bf16x8 af[4], bfv[4];
    #pragma unroll
    for (int mi = 0; mi < 4; mi++)
      af[mi] = *(const bf16x8*)&lA[cur][aoff[mi]];
    #pragma unroll
    for (int ni = 0; ni < 4; ni++)
      bfv[ni] = *(const bf16x8*)&lB[cur][boff[ni]];
    __builtin_amdgcn_s_setprio(1);
    #pragma unroll
    for (int mi = 0; mi < 4; mi++)
      #pragma unroll
      for (int ni = 0; ni < 4; ni++)
        acc[mi][ni] = __builtin_amdgcn_mfma_f32_16x16x32_bf16(af[mi], bfv[ni], acc[mi][ni], 0, 0, 0);
    __builtin_amdgcn_s_setprio(0);
    cur ^= 1;
  }
#undef STAGE_G

  int seg = n0 >> 9;                       // 0=Q, 1=K, 2=V
  const float* bp = (seg == 0) ? bq : (seg == 1) ? bk : bv;
  u16* op = (seg == 0) ? Qb : (seg == 1) ? Kb : Vb;
  float aeff = (seg == 0) ? 0.125f * LOG2E : 1.0f;

  #pragma unroll
  for (int mi = 0; mi < 4; mi++)
    #pragma unroll
    for (int ni = 0; ni < 4; ni++) {
      int col = n0 + wc*64 + ni*16 + lrow;
      int ocol = col & 511;
      float bvv = bp[ocol];
      #pragma unroll
      for (int r = 0; r < 4; r++) {
        int row = m0 + wr*64 + mi*16 + kg*4 + r;
        float v = (acc[mi][ni][r] + bvv) * aeff;
        op[(size_t)row * 512 + ocol] = f2bf(v);
      }
    }
}

// ---------------- flash attention v11: 8-wave blocks, 256 q-rows, shared K/V staging ----------------
__global__ __launch_bounds__(512) void attn_kernel(
    const u16* __restrict__ Q, const u16* __restrict__ Km,
    const u16* __restrict__ Vm, const float* __restrict__ mask,
    u16* __restrict__ ctx) {
  __shared__ u16 lK[2][4096];     // [key 64][dh 64], dword-swizzled, 128B rows
  __shared__ u16 lV[2][4096];     // [dh 64][key 64] transposed, dword-swizzled
  __shared__ float lBias[1024];
  int tid = threadIdx.x, lane = tid & 63, wid = tid >> 6;   // wid 0..7
  int la = lane & 31, hi = lane >> 5;
  int wg = blockIdx.x;
  int xcd = wg & 7, idx = wg >> 3;      // idx 0..63
  int bh = xcd * 16 + (idx & 15);
  int qt = idx >> 4;                    // 0..3 (256-row q tiles)
  int b = bh >> 3, h = bh & 7;
  bool vwave = (wid < 4);               // wave-uniform staging split
  int tid2 = tid & 255;                 // K-staging index for waves 4-7

  const u16* qp = Q + (size_t)(b*S_ + qt*256 + wid*32 + la) * D_ + h*DH_ + hi*8;
  bf16x8 qf[4];
  #pragma unroll
  for (int c = 0; c < 4; c++) qf[c] = *(const bf16x8*)(qp + c*16);

  int krow = tid2 >> 3;                 // 0..31 (K rows, +32 second call)
  int kcol = 8 * (tid2 & 7);
  int kc0 = kcol ^ (swz3(krow) << 3);
  int kc1 = kcol ^ (swz3(krow + 32) << 3);
  int va = tid & 7, vp = (tid >> 3) & 31;   // V staging map (waves 0-3: tid<256)
  const u16* kbase = Km + ((size_t)b*S_) * D_ + h*DH_;
  const u16* vbase = Vm + ((size_t)b*S_) * D_ + h*DH_ + 8*va;

#define STAGE_K(buf, tt) do { \
    const u16* kt_ = kbase + (size_t)(tt)*64*D_; \
    gload16(kt_ + (size_t)krow*D_ + kc0,        &lK[buf][tid2*8]); \
    gload16(kt_ + (size_t)(krow+32)*D_ + kc1,   &lK[buf][2048 + tid2*8]); \
  } while (0)
#define LOAD_V(tt) do { \
    const u16* vt_ = vbase + (size_t)((tt)*64 + 2*vp) * D_; \
    nv0 = *(const bf16x8*)vt_; nv1 = *(const bf16x8*)(vt_ + D_); \
  } while (0)
#define WRITE_V(buf) do { \
    u32* lVd_ = (u32*)lV[buf]; \
    _Pragma("unroll") \
    for (int jv = 0; jv < 8; jv++) { \
      int row_ = 8*va + jv; \
      u32 pv_ = (u32)(u16)nv0[jv] | ((u32)(u16)nv1[jv] << 16); \
      lVd_[row_*32 + (vp ^ (swz3(row_) << 2))] = pv_; \
    } \
  } while (0)

  int swk0 = swz3(la) << 2, swk1 = swz3(la + 32) << 2;
  f32x16 oc0, oc1;
  #pragma unroll
  for (int i = 0; i < 16; i++) { oc0[i] = 0.f; oc1[i] = 0.f; }
  float lsum = 0.f;

#define QKT(d0, d1, tt) do { \
    _Pragma("unroll") \
    for (int rq = 0; rq < 4; rq++) { \
      f32x4 bb0 = *(const f32x4*)&lBias[(tt)*64 + rq*8 + hi*4]; \
      f32x4 bb1 = *(const f32x4*)&lBias[(tt)*64 + 32 + rq*8 + hi*4]; \
      _Pragma("unroll") \
      for (int jj = 0; jj < 4; jj++) { d0[rq*4+jj] = bb0[jj]; d1[rq*4+jj] = bb1[jj]; } \
    } \
    { const u16* lkb_ = lK[(tt)&1]; \
      __builtin_amdgcn_s_setprio(1); \
      _Pragma("unroll") \
      for (int c_ = 0; c_ < 4; c_++) { \
        int dwb_ = c_*8 + hi*4; \
        bf16x8 kf0_ = *(const bf16x8*)&lkb_[la*64 + ((dwb_ ^ swk0) << 1)]; \
        bf16x8 kf1_ = *(const bf16x8*)&lkb_[(la+32)*64 + ((dwb_ ^ swk1) << 1)]; \
        d0 = __builtin_amdgcn_mfma_f32_32x32x16_bf16(kf0_, qf[c_], d0, 0, 0, 0); \
        d1 = __builtin_amdgcn_mfma_f32_32x32x16_bf16(kf1_, qf[c_], d1, 0, 0, 0); \
      } \
      __builtin_amdgcn_s_setprio(0); } \
  } while (0)

#define SOFTPV(s0v, s1v, tt) do { \
    float rsp_[4] = {0.f, 0.f, 0.f, 0.f}; \
    _Pragma("unroll") \
    for (int i_ = 0; i_ < 16; i_++) { float e_ = exp2fast(s0v[i_]); s0v[i_] = e_; rsp_[i_ & 3] += e_; } \
    _Pragma("unroll") \
    for (int i_ = 0; i_ < 16; i_++) { float e_ = exp2fast(s1v[i_]); s1v[i_] = e_; rsp_[i_ & 3] += e_; } \
    lsum += (rsp_[0] + rsp_[1]) + (rsp_[2] + rsp_[3]); \
    { const u16* lvb_ = lV[(tt)&1]; \
      __builtin_amdgcn_s_setprio(1); \
      _Pragma("unroll") \
      for (int cc_ = 0; cc_ < 4; cc_++) { \
        const int base_ = 8 * (cc_ & 1); \
        float pv_[8]; \
        _Pragma("unroll") \
        for (int k_ = 0; k_ < 8; k_++) pv_[k_] = (cc_ < 2) ? s0v[base_ + k_] : s1v[base_ + k_]; \
        u32 a0_ = pk2(pv_[0], pv_[1]); \
        u32 a1_ = pk2(pv_[2], pv_[3]); \
        u32 b0_ = pk2(pv_[4], pv_[5]); \
        u32 b1_ = pk2(pv_[6], pv_[7]); \
        union { u32 u[4]; bf16x8 v; } pf_; \
        PEXCH(pf_, a0_, a1_, b0_, b1_); \
        _Pragma("unroll") \
        for (int vb_ = 0; vb_ < 2; vb_++) { \
          int row_ = vb_*32 + la; \
          int dwv_ = (cc_*8 + hi*4) ^ (swz3(row_) << 2); \
          bf16x8 vf_ = *(const bf16x8*)&lvb_[row_*64 + (dwv_ << 1)]; \
          if (vb_ == 0) oc0 = __builtin_amdgcn_mfma_f32_32x32x16_bf16(pf_.v, vf_, oc0, 0, 0, 0); \
          else          oc1 = __builtin_amdgcn_mfma_f32_32x32x16_bf16(pf_.v, vf_, oc1, 0, 0, 0); \
        } \
      } \
      __builtin_amdgcn_s_setprio(0); } \
  } while (0)

#ifdef HAVE_PLS
#define PEXCH(pf_, a0_, a1_, b0_, b1_) do { \
    u32x2 r0_ = __builtin_amdgcn_permlane32_swap(a0_, b0_, false, false); \
    u32x2 r1_ = __builtin_amdgcn_permlane32_swap(a1_, b1_, false, false); \
    pf_.u[0] = r0_[0]; pf_.u[1] = r1_[0]; pf_.u[2] = r0_[1]; pf_.u[3] = r1_[1]; \
  } while (0)
#else
#define PEXCH(pf_, a0_, a1_, b0_, b1_) do { \
    u32 sd0_ = hi ? a0_ : b0_, sd1_ = hi ? a1_ : b1_; \
    u32 x0_ = (u32)__shfl_xor((int)sd0_, 32); \
    u32 x1_ = (u32)__shfl_xor((int)sd1_, 32); \
    pf_.u[0] = hi ? x0_ : a0_; \
    pf_.u[1] = hi ? x1_ : a1_; \
    pf_.u[2] = hi ? b0_ : x0_; \
    pf_.u[3] = hi ? b1_ : x1_; \
  } while (0)
#endif

  // ---- prologue: waves 0-3 stage V0 + bias, load V1; waves 4-7 DMA K0,K1 ----
  bf16x8 nv0, nv1;
  if (vwave) {
    f32x4 mv = ((const f32x4*)(mask + (size_t)b*S_))[tid];
    f32x4 bv;
    #pragma unroll
    for (int jj = 0; jj < 4; jj++) bv[jj] = mv[jj] * (-1.0e9f * LOG2E);
    ((f32x4*)lBias)[tid] = bv;
    LOAD_V(0);
    WRITE_V(0);
    LOAD_V(1);
  } else {
    STAGE_K(0, 0);
    STAGE_K(1, 1);
  }
  __syncthreads();

  f32x16 sA0, sA1, sB0, sB1;
  QKT(sA0, sA1, 0);
  __syncthreads();          // all waves done reading lK[0] before iter0 re-DMAs it

  // ---- pipelined main loop, unrolled by 2 (A/B score states) ----
  for (int t = 0; t < NT_; t += 2) {
    if (!vwave) { if (t + 2 < NT_) STAGE_K(t & 1, t + 2); }
    if (vwave) {
      WRITE_V((t + 1) & 1);
      if (t + 2 < NT_) LOAD_V(t + 2);
    }
    QKT(sB0, sB1, t + 1);
    SOFTPV(sA0, sA1, t);
    __syncthreads();
    {
      int u = t + 1;
      if (!vwave) { if (u + 2 < NT_) STAGE_K(u & 1, u + 2); }
      if (vwave) {
        if (u + 1 < NT_) WRITE_V((u + 1) & 1);
        if (u + 2 < NT_) LOAD_V(u + 2);
      }
      if (u + 1 < NT_) QKT(sA0, sA1, u + 1);
      SOFTPV(sB0, sB1, u);
      __syncthreads();
    }
  }
#undef STAGE_K
#undef LOAD_V
#undef WRITE_V
#undef QKT
#undef SOFTPV
#undef PEXCH

  // ---- epilogue ----
  lsum += __shfl_xor(lsum, 32);
  float linv = 1.f / lsum;
  #pragma unroll
  for (int r = 0; r < 16; r++) {
    int qr = (r&3) + 8*(r>>2) + 4*hi;
    float lr = __shfl(linv, qr);
    size_t rowoff = (size_t)(b*S_ + qt*256 + wid*32 + qr) * D_ + h*DH_;
    ctx[rowoff + la]      = f2bf(oc0[r] * lr);
    ctx[rowoff + 32 + la] = f2bf(oc1[r] * lr);
  }
}

// ---------------- LayerNorm apply (bf16 input; partials from GEMM epilogue) ----------------
template<bool WB, bool WF>
__global__ __launch_bounds__(256) void ln_apply_kernel(
    const u16* __restrict__ r, const float* __restrict__ part,
    const float* __restrict__ w, const float* __restrict__ bb,
    float* __restrict__ outF, u16* __restrict__ outB) {
  int b = blockIdx.y, c = blockIdx.x, tid = threadIdx.x;
  float s = 0.f, q = 0.f;
  for (int i = 0; i < 32; i++) { s += part[(b*32+i)*2]; q += part[(b*32+i)*2+1]; }
  const float inv = 1.f / (float)SD_;
  float mean = s * inv;
  float var = q * inv - mean * mean;
  float rs = rsqrtf(var + 1e-5f);
  size_t base = (size_t)b * SD_;
  #pragma unroll
  for (int i = 0; i < 8; i++) {
    int li4 = c*2048 + i*256 + tid;   // 4-elem index within slab
    u16x4 rv = ((const u16x4*)(r + base))[li4];
    f32x4 wv = ((const f32x4*)w)[li4];
    f32x4 bv = ((const f32x4*)bb)[li4];
    f32x4 ov;
    #pragma unroll
    for (int jj = 0; jj < 4; jj++) ov[jj] = (bf2f(rv[jj]) - mean) * rs * wv[jj] + bv[jj];
    if (WF) ((f32x4*)(outF + base))[li4] = ov;
    if (WB) {
      u16x4 ub = { f2bf(ov[0]), f2bf(ov[1]), f2bf(ov[2]), f2bf(ov[3]) };
      ((u16x4*)(outB + base))[li4] = ub;
    }
  }
}

// ---------------- launch ----------------
extern "C" void kernel_launch(void* const* d_in, const int* in_sizes, int n_in,
                              void* d_out, int out_size, void* d_ws, size_t ws_size,
                              hipStream_t stream) {
  (void)in_sizes; (void)n_in; (void)out_size; (void)ws_size;
  const float* x    = (const float*)d_in[0];
  const float* mask = (const float*)d_in[1];
  const float* wq = (const float*)d_in[2];
  const float* bq = (const float*)d_in[3];
  const float* wk = (const float*)d_in[4];
  const float* bk = (const float*)d_in[5];
  const float* wv = (const float*)d_in[6];
  const float* bv = (const float*)d_in[7];
  const float* wo = (const float*)d_in[8];
  const float* bo = (const float*)d_in[9];
  const float* w1 = (const float*)d_in[10];
  const float* b1 = (const float*)d_in[11];
  const float* w2 = (const float*)d_in[12];
  const float* b2 = (const float*)d_in[13];
  const float* ln1w = (const float*)d_in[14];
  const float* ln1b = (const float*)d_in[15];
  const float* ln2w = (const float*)d_in[16];
  const float* ln2b = (const float*)d_in[17];
  float* out = (float*)d_out;

  char* ws = (char*)d_ws;
  const size_t MB = 1ull << 20;
  u16*   xb    = (u16*)(ws + 0);
  u16*   Qb    = (u16*)(ws + 16*MB);
  u16*   Kb    = (u16*)(ws + 32*MB);
  u16*   Vb    = (u16*)(ws + 48*MB);
  u16*   ctxb  = (u16*)(ws + 64*MB);
  u16*   res1b = (u16*)(ws + 80*MB);
  u16*   out1b = (u16*)(ws + 0);        // reuse xb (xb fully consumed by O-proj residual read)
  u16*   ffn1  = (u16*)(ws + 16*MB);    // reuse Q/K/V/ctx (dead after O-proj)
  u16*   res2b = (u16*)(ws + 112*MB);
  float* part  = (float*)(ws + 144*MB);
  u16*   wqkvT = (u16*)(ws + 145*MB);   // [1536][512] bf16
  u16*   woT   = (u16*)(ws + 147*MB);
  u16*   w1T   = (u16*)(ws + 148*MB);
  u16*   w2T   = (u16*)(ws + 150*MB);

  // fused prep: cast x + all 6 weight transposes
  prep_kernel<<<11264, 256, 0, stream>>>(
      x, xb, wq, wk, wv, wo, w1, w2, wqkvT, woT, w1T, w2T);

  // fused QKV projection: 128^2 split kernel, grid 1536 (nx=12, ypg=16)
  gemm128_qkv_kernel<<<1536, 256, 0, stream>>>(
      xb, wqkvT, bq, bk, bv, Qb, Kb, Vb, 512, 12, 16);

  attn_kernel<<<512, 512, 0, stream>>>(Qb, Kb, Vb, mask, ctxb);

  // O-proj: 128^2, residual = xb (bf16), bf16 out + fused LN1 partials. grid 512
  gemm_kernel<1,false,true><<<512, 256, 0, stream>>>(
      ctxb, woT, bo, nullptr, xb, res1b, part, 512, 512, 4, 16);

  ln_apply_kernel<true,false><<<dim3(64,16), 256, 0, stream>>>(
      res1b, part, ln1w, ln1b, nullptr, out1b);

  // FFN1: 128x256 8-wave + ReLU, grid 1024 (nx=8, ypg=16) — 2x barrier amortization
  gemm128x256_kernel<true><<<1024, 512, 0, stream>>>(
      out1b, w1T, b1, ffn1, 512, 2048, 8, 16);

  // FFN2: 128^2, residual = out1b (bf16), bf16 out + fused LN2 partials. grid 512
  gemm_kernel<1,false,true><<<512, 256, 0, stream>>>(
      ffn1, w2T, b2, nullptr, out1b, res2b, part, 2048, 512, 4, 16);

  ln_apply_kernel<false,true><<<dim3(64,16), 256, 0, stream>>>(
      res2b, part, ln2w, ln2b, out, nullptr);
}

// Round 21
// 215.840 us; speedup vs baseline: 1.1032x; 1.0509x over previous
//
#include <hip/hip_runtime.h>
#include <stdint.h>

#define B_   16
#define S_   1024
#define D_   512
#define H_   8
#define DH_  64
#define DFF_ 2048
#define M_   (B_*S_)     // 16384
#define SD_  (S_*D_)     // 524288
#define NT_  16          // S_/64 KV tiles

typedef unsigned short u16;
typedef unsigned int u32;
typedef __attribute__((ext_vector_type(2))) unsigned int u32x2;
typedef __attribute__((ext_vector_type(4))) unsigned short u16x4;
typedef __attribute__((ext_vector_type(8))) short bf16x8;
typedef __attribute__((ext_vector_type(4))) float f32x4;
typedef __attribute__((ext_vector_type(16))) float f32x16;

#define LOG2E 1.4426950408889634f

#if defined(__has_builtin)
#if __has_builtin(__builtin_amdgcn_permlane32_swap)
#define HAVE_PLS 1
#endif
#endif

__device__ __forceinline__ u16 f2bf(float f) {
  union { float f; uint32_t u; } x{f};
  uint32_t r = x.u + 0x7fffu + ((x.u >> 16) & 1u);
  return (u16)(r >> 16);
}

__device__ __forceinline__ float bf2f(u16 v) {
  union { uint32_t u; float f; } x{(uint32_t)v << 16};
  return x.f;
}

// pack hi16(a), hi16(b) -> dword (truncating bf16 pair) via v_perm_b32
__device__ __forceinline__ u32 pk2(float lo, float hi) {
  union { float f; u32 u; } a{lo}, b{hi};
  return __builtin_amdgcn_perm(b.u, a.u, 0x07060302u);
}

__device__ __forceinline__ float exp2fast(float x) {
#if __has_builtin(__builtin_amdgcn_exp2f)
  return __builtin_amdgcn_exp2f(x);
#else
  return exp2f(x);
#endif
}

__device__ __forceinline__ void gload16(const u16* g, u16* l) {
  __builtin_amdgcn_global_load_lds(
      (const __attribute__((address_space(1))) uint32_t*)g,
      (__attribute__((address_space(3))) uint32_t*)l, 16, 0, 0);
}

__device__ __forceinline__ int swz3(int r) { return (r & 7) ^ ((r >> 3) & 7); }

// ---------------- fused prep: cast x + all 6 weight transposes, one dispatch ----------------
__global__ __launch_bounds__(256) void prep_kernel(
    const float* __restrict__ x, u16* __restrict__ xb,
    const float* __restrict__ wq, const float* __restrict__ wk,
    const float* __restrict__ wv, const float* __restrict__ wo,
    const float* __restrict__ w1, const float* __restrict__ w2,
    u16* __restrict__ wqkvT, u16* __restrict__ woT,
    u16* __restrict__ w1T, u16* __restrict__ w2T) {
  int bid = blockIdx.x, tid = threadIdx.x;
  if (bid < 8192) {
    int i = bid * 256 + tid;
    f32x4 v = ((const f32x4*)x)[i];
    u16x4 o = { f2bf(v[0]), f2bf(v[1]), f2bf(v[2]), f2bf(v[3]) };
    ((u16x4*)xb)[i] = o;
    return;
  }
  bid -= 8192;
  const float* W; u16* WT; int K, N, bx, by;
  if (bid < 1024) {
    int which = bid >> 8;
    W  = (which == 0) ? wq : (which == 1) ? wk : (which == 2) ? wv : wo;
    WT = (which == 3) ? woT : (wqkvT + (size_t)which * 512 * 512);
    K = 512; N = 512;
    int r = bid & 255; bx = r & 15; by = r >> 4;
  } else if (bid < 2048) {
    int r = bid - 1024; W = w1; WT = w1T; K = 512; N = 2048;
    bx = r & 63; by = r >> 6;
  } else {
    int r = bid - 2048; W = w2; WT = w2T; K = 2048; N = 512;
    bx = r & 15; by = r >> 4;
  }
  __shared__ float t[32][33];
  int n0 = bx * 32, k0 = by * 32;
  int tx = tid & 31, ty = tid >> 5;
  #pragma unroll
  for (int i = 0; i < 4; i++)
    t[ty + 8*i][tx] = W[(size_t)(k0 + ty + 8*i) * N + n0 + tx];
  __syncthreads();
  #pragma unroll
  for (int i = 0; i < 4; i++)
    WT[(size_t)(n0 + ty + 8*i) * K + k0 + tx] = f2bf(t[tx][ty + 8*i]);
}

// ================= 128x128 BK=64 GEMM (O-proj / FFN2), 1 barrier per K-tile =================
// 8 LDS slots/row; swizzle slot' = slot ^ (row & 7); linear DMA dest + inverse-swizzled src.
// MODE 1 semantics: bf16 residual-sum out + fused LN partials.
__global__ __launch_bounds__(256) void gemm128_bk64_kernel(
    const u16* __restrict__ A, const u16* __restrict__ WT,
    const float* __restrict__ bias0, const u16* __restrict__ resB,
    u16* __restrict__ out0,
    float* __restrict__ partOut, int K, int N, int nx, int ypg) {
  __shared__ u16 lA[2][128 * 64];   // 32 KB
  __shared__ u16 lB[2][128 * 64];   // 32 KB
  __shared__ float lred[8];
  int tid = threadIdx.x;
  int lane = tid & 63, wid = tid >> 6;
  int wr = wid >> 1, wc = wid & 1;
  int lrow = lane & 15, kg = lane >> 4;

  int dd = blockIdx.x;
  int cc = dd & 7, jj = dd >> 3;
  int bx = jj % nx, by = cc * ypg + jj / nx;
  int m0 = by * 128, n0 = bx * 128;

  int r0 = tid >> 3;                               // 0..31 (+32j)
  int c0s = ((tid & 7) ^ (r0 & 7)) * 8;            // inverse-swizzled source col (j-invariant)
  const u16* agp = A  + (size_t)m0 * K;
  const u16* bgp = WT + (size_t)n0 * K;

  // kk=0 swizzled fragment offsets; kk=1 = offset ^ 32 (slot^4 identity)
  int aoff[4], boff[4];
  #pragma unroll
  for (int mi = 0; mi < 4; mi++) {
    int row = wr*64 + mi*16 + lrow;
    aoff[mi] = row*64 + ((kg ^ (row & 7)) * 8);
  }
  #pragma unroll
  for (int ni = 0; ni < 4; ni++) {
    int row = wc*64 + ni*16 + lrow;
    boff[ni] = row*64 + ((kg ^ (row & 7)) * 8);
  }

  f32x4 z = {0.f, 0.f, 0.f, 0.f};
  f32x4 acc[4][4];
  #pragma unroll
  for (int mi = 0; mi < 4; mi++)
    #pragma unroll
    for (int ni = 0; ni < 4; ni++) acc[mi][ni] = z;

#define STG64(buf, kt) do { \
    _Pragma("unroll") \
    for (int j = 0; j < 4; j++) { \
      gload16(agp + (size_t)(r0 + j*32) * K + (kt) + c0s, &lA[buf][(tid + j*256) * 8]); \
      gload16(bgp + (size_t)(r0 + j*32) * K + (kt) + c0s, &lB[buf][(tid + j*256) * 8]); \
    } \
  } while (0)

  STG64(0, 0);

  int nk = K / 64;
  int cur = 0;
  for (int t = 0; t < nk; t++) {
    __syncthreads();                       // single sync point per tile
    if (t + 1 < nk) STG64(cur ^ 1, (t + 1) * 64);
    #pragma unroll
    for (int kk = 0; kk < 2; kk++) {
      int xr = kk ? 32 : 0;
      bf16x8 af[4], bfv[4];
      #pragma unroll
      for (int mi = 0; mi < 4; mi++)
        af[mi] = *(const bf16x8*)&lA[cur][aoff[mi] ^ xr];
      #pragma unroll
      for (int ni = 0; ni < 4; ni++)
        bfv[ni] = *(const bf16x8*)&lB[cur][boff[ni] ^ xr];
      __builtin_amdgcn_s_setprio(1);
      #pragma unroll
      for (int mi = 0; mi < 4; mi++)
        #pragma unroll
        for (int ni = 0; ni < 4; ni++)
          acc[mi][ni] = __builtin_amdgcn_mfma_f32_16x16x32_bf16(af[mi], bfv[ni], acc[mi][ni], 0, 0, 0);
      __builtin_amdgcn_s_setprio(0);
    }
    cur ^= 1;
  }
#undef STG64

  float s_acc = 0.f, q_acc = 0.f;
  #pragma unroll
  for (int mi = 0; mi < 4; mi++)
    #pragma unroll
    for (int ni = 0; ni < 4; ni++) {
      int col = n0 + wc*64 + ni*16 + lrow;
      float bv = bias0[col];
      #pragma unroll
      for (int r = 0; r < 4; r++) {
        int row = m0 + wr*64 + mi*16 + kg*4 + r;
        size_t off = (size_t)row * N + col;
        float tv = acc[mi][ni][r] + bv + bf2f(resB[off]);
        out0[off] = f2bf(tv);
        s_acc += tv;
        q_acc += tv * tv;
      }
    }

  #pragma unroll
  for (int dsh = 1; dsh < 64; dsh <<= 1) {
    s_acc += __shfl_xor(s_acc, dsh);
    q_acc += __shfl_xor(q_acc, dsh);
  }
  if (lane == 0) { lred[wid*2] = s_acc; lred[wid*2+1] = q_acc; }
  __syncthreads();
  if (tid == 0) {
    int batch = by >> 3;
    int pidx = batch*32 + (by & 7)*nx + bx;
    partOut[pidx*2]   = lred[0]+lred[2]+lred[4]+lred[6];
    partOut[pidx*2+1] = lred[1]+lred[3]+lred[5]+lred[7];
  }
}

// ================= 128x256 8-wave GEMM (FFN1): 2x barrier amortization =================
template<bool RELU>
__global__ __launch_bounds__(512, 4) void gemm128x256_kernel(
    const u16* __restrict__ A, const u16* __restrict__ WT,
    const float* __restrict__ bias0,
    u16* __restrict__ out0, int K, int N, int nx, int ypg) {
  __shared__ u16 lA[2][128 * 32];   // 16 KB
  __shared__ u16 lB[2][256 * 32];   // 32 KB
  int tid = threadIdx.x;
  int lane = tid & 63, wid = tid >> 6;
  int wr = wid >> 2, wc = wid & 3;          // 2M x 4N waves
  int lrow = lane & 15, kg = lane >> 4;

  int dd = blockIdx.x;
  int cc = dd & 7, jj = dd >> 3;
  int bx = jj % nx, by = cc * ypg + jj / nx;
  int m0 = by * 128, n0 = bx * 256;

  int r0 = tid >> 2;                               // 0..127
  int c0s = ((tid & 3) ^ ((r0 >> 1) & 3)) * 8;     // inverse-swizzled source col (+128 invariant)
  const u16* agp = A  + (size_t)m0 * K;
  const u16* bgp = WT + (size_t)n0 * K;

  int aoff[4], boff[4];
  #pragma unroll
  for (int mi = 0; mi < 4; mi++) {
    int row = wr*64 + mi*16 + lrow;
    aoff[mi] = row*32 + ((kg ^ ((row >> 1) & 3)) * 8);
  }
  #pragma unroll
  for (int ni = 0; ni < 4; ni++) {
    int row = wc*64 + ni*16 + lrow;                // 0..255
    boff[ni] = row*32 + ((kg ^ ((row >> 1) & 3)) * 8);
  }

  f32x4 z = {0.f, 0.f, 0.f, 0.f};
  f32x4 acc[4][4];
  #pragma unroll
  for (int mi = 0; mi < 4; mi++)
    #pragma unroll
    for (int ni = 0; ni < 4; ni++) acc[mi][ni] = z;

#define STG(buf, kt) do { \
    gload16(agp + (size_t)r0 * K + (kt) + c0s,         &lA[buf][tid * 8]); \
    gload16(bgp + (size_t)r0 * K + (kt) + c0s,         &lB[buf][tid * 8]); \
    gload16(bgp + (size_t)(r0 + 128) * K + (kt) + c0s, &lB[buf][4096 + tid * 8]); \
  } while (0)

  STG(0, 0);

  int nk = K / 32;
  int cur = 0;
  for (int t = 0; t < nk; t++) {
    __syncthreads();                 // single sync point per tile
    if (t + 1 < nk) STG(cur ^ 1, (t + 1) * 32);
    bf16x8 af[4], bfv[4];
    #pragma unroll
    for (int mi = 0; mi < 4; mi++)
      af[mi] = *(const bf16x8*)&lA[cur][aoff[mi]];
    #pragma unroll
    for (int ni = 0; ni < 4; ni++)
      bfv[ni] = *(const bf16x8*)&lB[cur][boff[ni]];
    __builtin_amdgcn_s_setprio(1);
    #pragma unroll
    for (int mi = 0; mi < 4; mi++)
      #pragma unroll
      for (int ni = 0; ni < 4; ni++)
        acc[mi][ni] = __builtin_amdgcn_mfma_f32_16x16x32_bf16(af[mi], bfv[ni], acc[mi][ni], 0, 0, 0);
    __builtin_amdgcn_s_setprio(0);
    cur ^= 1;
  }
#undef STG

  #pragma unroll
  for (int mi = 0; mi < 4; mi++)
    #pragma unroll
    for (int ni = 0; ni < 4; ni++) {
      int col = n0 + wc*64 + ni*16 + lrow;
      float bv = bias0[col];
      #pragma unroll
      for (int r = 0; r < 4; r++) {
        int row = m0 + wr*64 + mi*16 + kg*4 + r;
        float v = acc[mi][ni][r] + bv;
        if (RELU) v = fmaxf(v, 0.f);
        out0[(size_t)row * N + col] = f2bf(v);
      }
    }
}

// ================= 128x128 QKV GEMM (N=1536 split into Q/K/V, Q scaled), swizzled LDS =================
__global__ __launch_bounds__(256) void gemm128_qkv_kernel(
    const u16* __restrict__ A, const u16* __restrict__ WT,
    const float* __restrict__ bq, const float* __restrict__ bk,
    const float* __restrict__ bv,
    u16* __restrict__ Qb, u16* __restrict__ Kb, u16* __restrict__ Vb,
    int K, int nx, int ypg) {
  __shared__ u16 lA[2][128 * 32];
  __shared__ u16 lB[2][128 * 32];
  int tid = threadIdx.x;
  int lane = tid & 63, wid = tid >> 6;
  int wr = wid >> 1, wc = wid & 1;
  int lrow = lane & 15, kg = lane >> 4;

  int dd = blockIdx.x;
  int cc = dd & 7, jj = dd >> 3;
  int bx = jj % nx, by = cc * ypg + jj / nx;
  int m0 = by * 128, n0 = bx * 128;

  int r0 = tid >> 2;
  int c0s = ((tid & 3) ^ ((r0 >> 1) & 3)) * 8;
  const u16* agp = A  + (size_t)m0 * K;
  const u16* bgp = WT + (size_t)n0 * K;

  int aoff[4], boff[4];
  #pragma unroll
  for (int mi = 0; mi < 4; mi++) {
    int row = wr*64 + mi*16 + lrow;
    aoff[mi] = row*32 + ((kg ^ ((row >> 1) & 3)) * 8);
  }
  #pragma unroll
  for (int ni = 0; ni < 4; ni++) {
    int row = wc*64 + ni*16 + lrow;
    boff[ni] = row*32 + ((kg ^ ((row >> 1) & 3)) * 8);
  }

  f32x4 z = {0.f, 0.f, 0.f, 0.f};
  f32x4 acc[4][4];
  #pragma unroll
  for (int mi = 0; mi < 4; mi++)
    #pragma unroll
    for (int ni = 0; ni < 4; ni++) acc[mi][ni] = z;

#define STAGE_G(buf, kt) do { \
    gload16(agp + (size_t)r0 * K + (kt) + c0s,        &lA[buf][tid * 8]); \
    gload16(agp + (size_t)(r0 + 64) * K + (kt) + c0s, &lA[buf][2048 + tid * 8]); \
    gload16(bgp + (size_t)r0 * K + (kt) + c0s,        &lB[buf][tid * 8]); \
    gload16(bgp + (size_t)(r0 + 64) * K + (kt) + c0s, &lB[buf][2048 + tid * 8]); \
  } while (0)

  STAGE_G(0, 0);

  int nk = K / 32;
  int cur = 0;
  for (int t = 0; t < nk; t++) {
    __syncthreads();
    if (t + 1 < nk) STAGE_G(cur ^ 1, (t + 1) * 32);
    bf16x8 af[4], bfv[4];
    #pragma unroll
    for (int mi = 0; mi < 4; mi++)
      af[mi] = *(const bf16x8*)&lA[cur][aoff[mi]];
    #pragma unroll
    for (int ni = 0; ni < 4; ni++)
      bfv[ni] = *(const bf16x8*)&lB[cur][boff[ni]];
    __builtin_amdgcn_s_setprio(1);
    #pragma unroll
    for (int mi = 0; mi < 4; mi++)
      #pragma unroll
      for (int ni = 0; ni < 4; ni++)
        acc[mi][ni] = __builtin_amdgcn_mfma_f32_16x16x32_bf16(af[mi], bfv[ni], acc[mi][ni], 0, 0, 0);
    __builtin_amdgcn_s_setprio(0);
    cur ^= 1;
  }
#undef STAGE_G

  int seg = n0 >> 9;                       // 0=Q, 1=K, 2=V
  const float* bp = (seg == 0) ? bq : (seg == 1) ? bk : bv;
  u16* op = (seg == 0) ? Qb : (seg == 1) ? Kb : Vb;
  float aeff = (seg == 0) ? 0.125f * LOG2E : 1.0f;

  #pragma unroll
  for (int mi = 0; mi < 4; mi++)
    #pragma unroll
    for (int ni = 0; ni < 4; ni++) {
      int col = n0 + wc*64 + ni*16 + lrow;
      int ocol = col & 511;
      float bvv = bp[ocol];
      #pragma unroll
      for (int r = 0; r < 4; r++) {
        int row = m0 + wr*64 + mi*16 + kg*4 + r;
        float v = (acc[mi][ni][r] + bvv) * aeff;
        op[(size_t)row * 512 + ocol] = f2bf(v);
      }
    }
}

// ---------------- flash attention v11: 8-wave blocks, 256 q-rows, shared K/V staging ----------------
__global__ __launch_bounds__(512) void attn_kernel(
    const u16* __restrict__ Q, const u16* __restrict__ Km,
    const u16* __restrict__ Vm, const float* __restrict__ mask,
    u16* __restrict__ ctx) {
  __shared__ u16 lK[2][4096];     // [key 64][dh 64], dword-swizzled, 128B rows
  __shared__ u16 lV[2][4096];     // [dh 64][key 64] transposed, dword-swizzled
  __shared__ float lBias[1024];
  int tid = threadIdx.x, lane = tid & 63, wid = tid >> 6;   // wid 0..7
  int la = lane & 31, hi = lane >> 5;
  int wg = blockIdx.x;
  int xcd = wg & 7, idx = wg >> 3;      // idx 0..63
  int bh = xcd * 16 + (idx & 15);
  int qt = idx >> 4;                    // 0..3 (256-row q tiles)
  int b = bh >> 3, h = bh & 7;
  bool vwave = (wid < 4);               // wave-uniform staging split
  int tid2 = tid & 255;                 // K-staging index for waves 4-7

  const u16* qp = Q + (size_t)(b*S_ + qt*256 + wid*32 + la) * D_ + h*DH_ + hi*8;
  bf16x8 qf[4];
  #pragma unroll
  for (int c = 0; c < 4; c++) qf[c] = *(const bf16x8*)(qp + c*16);

  int krow = tid2 >> 3;                 // 0..31 (K rows, +32 second call)
  int kcol = 8 * (tid2 & 7);
  int kc0 = kcol ^ (swz3(krow) << 3);
  int kc1 = kcol ^ (swz3(krow + 32) << 3);
  int va = tid & 7, vp = (tid >> 3) & 31;   // V staging map (waves 0-3: tid<256)
  const u16* kbase = Km + ((size_t)b*S_) * D_ + h*DH_;
  const u16* vbase = Vm + ((size_t)b*S_) * D_ + h*DH_ + 8*va;

#define STAGE_K(buf, tt) do { \
    const u16* kt_ = kbase + (size_t)(tt)*64*D_; \
    gload16(kt_ + (size_t)krow*D_ + kc0,        &lK[buf][tid2*8]); \
    gload16(kt_ + (size_t)(krow+32)*D_ + kc1,   &lK[buf][2048 + tid2*8]); \
  } while (0)
#define LOAD_V(tt) do { \
    const u16* vt_ = vbase + (size_t)((tt)*64 + 2*vp) * D_; \
    nv0 = *(const bf16x8*)vt_; nv1 = *(const bf16x8*)(vt_ + D_); \
  } while (0)
#define WRITE_V(buf) do { \
    u32* lVd_ = (u32*)lV[buf]; \
    _Pragma("unroll") \
    for (int jv = 0; jv < 8; jv++) { \
      int row_ = 8*va + jv; \
      u32 pv_ = (u32)(u16)nv0[jv] | ((u32)(u16)nv1[jv] << 16); \
      lVd_[row_*32 + (vp ^ (swz3(row_) << 2))] = pv_; \
    } \
  } while (0)

  int swk0 = swz3(la) << 2, swk1 = swz3(la + 32) << 2;
  f32x16 oc0, oc1;
  #pragma unroll
  for (int i = 0; i < 16; i++) { oc0[i] = 0.f; oc1[i] = 0.f; }
  float lsum = 0.f;

#define QKT(d0, d1, tt) do { \
    _Pragma("unroll") \
    for (int rq = 0; rq < 4; rq++) { \
      f32x4 bb0 = *(const f32x4*)&lBias[(tt)*64 + rq*8 + hi*4]; \
      f32x4 bb1 = *(const f32x4*)&lBias[(tt)*64 + 32 + rq*8 + hi*4]; \
      _Pragma("unroll") \
      for (int jj = 0; jj < 4; jj++) { d0[rq*4+jj] = bb0[jj]; d1[rq*4+jj] = bb1[jj]; } \
    } \
    { const u16* lkb_ = lK[(tt)&1]; \
      __builtin_amdgcn_s_setprio(1); \
      _Pragma("unroll") \
      for (int c_ = 0; c_ < 4; c_++) { \
        int dwb_ = c_*8 + hi*4; \
        bf16x8 kf0_ = *(const bf16x8*)&lkb_[la*64 + ((dwb_ ^ swk0) << 1)]; \
        bf16x8 kf1_ = *(const bf16x8*)&lkb_[(la+32)*64 + ((dwb_ ^ swk1) << 1)]; \
        d0 = __builtin_amdgcn_mfma_f32_32x32x16_bf16(kf0_, qf[c_], d0, 0, 0, 0); \
        d1 = __builtin_amdgcn_mfma_f32_32x32x16_bf16(kf1_, qf[c_], d1, 0, 0, 0); \
      } \
      __builtin_amdgcn_s_setprio(0); } \
  } while (0)

#define SOFTPV(s0v, s1v, tt) do { \
    float rsp_[4] = {0.f, 0.f, 0.f, 0.f}; \
    _Pragma("unroll") \
    for (int i_ = 0; i_ < 16; i_++) { float e_ = exp2fast(s0v[i_]); s0v[i_] = e_; rsp_[i_ & 3] += e_; } \
    _Pragma("unroll") \
    for (int i_ = 0; i_ < 16; i_++) { float e_ = exp2fast(s1v[i_]); s1v[i_] = e_; rsp_[i_ & 3] += e_; } \
    lsum += (rsp_[0] + rsp_[1]) + (rsp_[2] + rsp_[3]); \
    { const u16* lvb_ = lV[(tt)&1]; \
      __builtin_amdgcn_s_setprio(1); \
      _Pragma("unroll") \
      for (int cc_ = 0; cc_ < 4; cc_++) { \
        const int base_ = 8 * (cc_ & 1); \
        float pv_[8]; \
        _Pragma("unroll") \
        for (int k_ = 0; k_ < 8; k_++) pv_[k_] = (cc_ < 2) ? s0v[base_ + k_] : s1v[base_ + k_]; \
        u32 a0_ = pk2(pv_[0], pv_[1]); \
        u32 a1_ = pk2(pv_[2], pv_[3]); \
        u32 b0_ = pk2(pv_[4], pv_[5]); \
        u32 b1_ = pk2(pv_[6], pv_[7]); \
        union { u32 u[4]; bf16x8 v; } pf_; \
        PEXCH(pf_, a0_, a1_, b0_, b1_); \
        _Pragma("unroll") \
        for (int vb_ = 0; vb_ < 2; vb_++) { \
          int row_ = vb_*32 + la; \
          int dwv_ = (cc_*8 + hi*4) ^ (swz3(row_) << 2); \
          bf16x8 vf_ = *(const bf16x8*)&lvb_[row_*64 + (dwv_ << 1)]; \
          if (vb_ == 0) oc0 = __builtin_amdgcn_mfma_f32_32x32x16_bf16(pf_.v, vf_, oc0, 0, 0, 0); \
          else          oc1 = __builtin_amdgcn_mfma_f32_32x32x16_bf16(pf_.v, vf_, oc1, 0, 0, 0); \
        } \
      } \
      __builtin_amdgcn_s_setprio(0); } \
  } while (0)

#ifdef HAVE_PLS
#define PEXCH(pf_, a0_, a1_, b0_, b1_) do { \
    u32x2 r0_ = __builtin_amdgcn_permlane32_swap(a0_, b0_, false, false); \
    u32x2 r1_ = __builtin_amdgcn_permlane32_swap(a1_, b1_, false, false); \
    pf_.u[0] = r0_[0]; pf_.u[1] = r1_[0]; pf_.u[2] = r0_[1]; pf_.u[3] = r1_[1]; \
  } while (0)
#else
#define PEXCH(pf_, a0_, a1_, b0_, b1_) do { \
    u32 sd0_ = hi ? a0_ : b0_, sd1_ = hi ? a1_ : b1_; \
    u32 x0_ = (u32)__shfl_xor((int)sd0_, 32); \
    u32 x1_ = (u32)__shfl_xor((int)sd1_, 32); \
    pf_.u[0] = hi ? x0_ : a0_; \
    pf_.u[1] = hi ? x1_ : a1_; \
    pf_.u[2] = hi ? b0_ : x0_; \
    pf_.u[3] = hi ? b1_ : x1_; \
  } while (0)
#endif

  // ---- prologue: waves 0-3 stage V0 + bias, load V1; waves 4-7 DMA K0,K1 ----
  bf16x8 nv0, nv1;
  if (vwave) {
    f32x4 mv = ((const f32x4*)(mask + (size_t)b*S_))[tid];
    f32x4 bv;
    #pragma unroll
    for (int jj = 0; jj < 4; jj++) bv[jj] = mv[jj] * (-1.0e9f * LOG2E);
    ((f32x4*)lBias)[tid] = bv;
    LOAD_V(0);
    WRITE_V(0);
    LOAD_V(1);
  } else {
    STAGE_K(0, 0);
    STAGE_K(1, 1);
  }
  __syncthreads();

  f32x16 sA0, sA1, sB0, sB1;
  QKT(sA0, sA1, 0);
  __syncthreads();          // all waves done reading lK[0] before iter0 re-DMAs it

  // ---- pipelined main loop, unrolled by 2 (A/B score states) ----
  for (int t = 0; t < NT_; t += 2) {
    if (!vwave) { if (t + 2 < NT_) STAGE_K(t & 1, t + 2); }
    if (vwave) {
      WRITE_V((t + 1) & 1);
      if (t + 2 < NT_) LOAD_V(t + 2);
    }
    QKT(sB0, sB1, t + 1);
    SOFTPV(sA0, sA1, t);
    __syncthreads();
    {
      int u = t + 1;
      if (!vwave) { if (u + 2 < NT_) STAGE_K(u & 1, u + 2); }
      if (vwave) {
        if (u + 1 < NT_) WRITE_V((u + 1) & 1);
        if (u + 2 < NT_) LOAD_V(u + 2);
      }
      if (u + 1 < NT_) QKT(sA0, sA1, u + 1);
      SOFTPV(sB0, sB1, u);
      __syncthreads();
    }
  }
#undef STAGE_K
#undef LOAD_V
#undef WRITE_V
#undef QKT
#undef SOFTPV
#undef PEXCH

  // ---- epilogue ----
  lsum += __shfl_xor(lsum, 32);
  float linv = 1.f / lsum;
  #pragma unroll
  for (int r = 0; r < 16; r++) {
    int qr = (r&3) + 8*(r>>2) + 4*hi;
    float lr = __shfl(linv, qr);
    size_t rowoff = (size_t)(b*S_ + qt*256 + wid*32 + qr) * D_ + h*DH_;
    ctx[rowoff + la]      = f2bf(oc0[r] * lr);
    ctx[rowoff + 32 + la] = f2bf(oc1[r] * lr);
  }
}

// ---------------- LayerNorm apply (bf16 input; partials from GEMM epilogue) ----------------
template<bool WB, bool WF>
__global__ __launch_bounds__(256) void ln_apply_kernel(
    const u16* __restrict__ r, const float* __restrict__ part,
    const float* __restrict__ w, const float* __restrict__ bb,
    float* __restrict__ outF, u16* __restrict__ outB) {
  int b = blockIdx.y, c = blockIdx.x, tid = threadIdx.x;
  float s = 0.f, q = 0.f;
  for (int i = 0; i < 32; i++) { s += part[(b*32+i)*2]; q += part[(b*32+i)*2+1]; }
  const float inv = 1.f / (float)SD_;
  float mean = s * inv;
  float var = q * inv - mean * mean;
  float rs = rsqrtf(var + 1e-5f);
  size_t base = (size_t)b * SD_;
  #pragma unroll
  for (int i = 0; i < 8; i++) {
    int li4 = c*2048 + i*256 + tid;   // 4-elem index within slab
    u16x4 rv = ((const u16x4*)(r + base))[li4];
    f32x4 wv = ((const f32x4*)w)[li4];
    f32x4 bv = ((const f32x4*)bb)[li4];
    f32x4 ov;
    #pragma unroll
    for (int jj = 0; jj < 4; jj++) ov[jj] = (bf2f(rv[jj]) - mean) * rs * wv[jj] + bv[jj];
    if (WF) ((f32x4*)(outF + base))[li4] = ov;
    if (WB) {
      u16x4 ub = { f2bf(ov[0]), f2bf(ov[1]), f2bf(ov[2]), f2bf(ov[3]) };
      ((u16x4*)(outB + base))[li4] = ub;
    }
  }
}

// ---------------- launch ----------------
extern "C" void kernel_launch(void* const* d_in, const int* in_sizes, int n_in,
                              void* d_out, int out_size, void* d_ws, size_t ws_size,
                              hipStream_t stream) {
  (void)in_sizes; (void)n_in; (void)out_size; (void)ws_size;
  const float* x    = (const float*)d_in[0];
  const float* mask = (const float*)d_in[1];
  const float* wq = (const float*)d_in[2];
  const float* bq = (const float*)d_in[3];
  const float* wk = (const float*)d_in[4];
  const float* bk = (const float*)d_in[5];
  const float* wv = (const float*)d_in[6];
  const float* bv = (const float*)d_in[7];
  const float* wo = (const float*)d_in[8];
  const float* bo = (const float*)d_in[9];
  const float* w1 = (const float*)d_in[10];
  const float* b1 = (const float*)d_in[11];
  const float* w2 = (const float*)d_in[12];
  const float* b2 = (const float*)d_in[13];
  const float* ln1w = (const float*)d_in[14];
  const float* ln1b = (const float*)d_in[15];
  const float* ln2w = (const float*)d_in[16];
  const float* ln2b = (const float*)d_in[17];
  float* out = (float*)d_out;

  char* ws = (char*)d_ws;
  const size_t MB = 1ull << 20;
  u16*   xb    = (u16*)(ws + 0);
  u16*   Qb    = (u16*)(ws + 16*MB);
  u16*   Kb    = (u16*)(ws + 32*MB);
  u16*   Vb    = (u16*)(ws + 48*MB);
  u16*   ctxb  = (u16*)(ws + 64*MB);
  u16*   res1b = (u16*)(ws + 80*MB);
  u16*   out1b = (u16*)(ws + 0);        // reuse xb (xb fully consumed by O-proj residual read)
  u16*   ffn1  = (u16*)(ws + 16*MB);    // reuse Q/K/V/ctx (dead after O-proj)
  u16*   res2b = (u16*)(ws + 112*MB);
  float* part  = (float*)(ws + 144*MB);
  u16*   wqkvT = (u16*)(ws + 145*MB);   // [1536][512] bf16
  u16*   woT   = (u16*)(ws + 147*MB);
  u16*   w1T   = (u16*)(ws + 148*MB);
  u16*   w2T   = (u16*)(ws + 150*MB);

  // fused prep: cast x + all 6 weight transposes
  prep_kernel<<<11264, 256, 0, stream>>>(
      x, xb, wq, wk, wv, wo, w1, w2, wqkvT, woT, w1T, w2T);

  // fused QKV projection: 128^2 split kernel, grid 1536 (nx=12, ypg=16)
  gemm128_qkv_kernel<<<1536, 256, 0, stream>>>(
      xb, wqkvT, bq, bk, bv, Qb, Kb, Vb, 512, 12, 16);

  attn_kernel<<<512, 512, 0, stream>>>(Qb, Kb, Vb, mask, ctxb);

  // O-proj: 128^2 BK=64, residual = xb (bf16), bf16 out + fused LN1 partials. grid 512
  gemm128_bk64_kernel<<<512, 256, 0, stream>>>(
      ctxb, woT, bo, xb, res1b, part, 512, 512, 4, 16);

  ln_apply_kernel<true,false><<<dim3(64,16), 256, 0, stream>>>(
      res1b, part, ln1w, ln1b, nullptr, out1b);

  // FFN1: 128x256 8-wave + ReLU, grid 1024 (nx=8, ypg=16)
  gemm128x256_kernel<true><<<1024, 512, 0, stream>>>(
      out1b, w1T, b1, ffn1, 512, 2048, 8, 16);

  // FFN2: 128^2 BK=64, residual = out1b (bf16), bf16 out + fused LN2 partials. grid 512
  gemm128_bk64_kernel<<<512, 256, 0, stream>>>(
      ffn1, w2T, b2, out1b, res2b, part, 2048, 512, 4, 16);

  ln_apply_kernel<false,true><<<dim3(64,16), 256, 0, stream>>>(
      res2b, part, ln2w, ln2b, out, nullptr);
}

// Round 22
// 214.860 us; speedup vs baseline: 1.1082x; 1.0046x over previous
//
#include <hip/hip_runtime.h>
#include <stdint.h>

#define B_   16
#define S_   1024
#define D_   512
#define H_   8
#define DH_  64
#define DFF_ 2048
#define M_   (B_*S_)     // 16384
#define SD_  (S_*D_)     // 524288
#define NT_  16          // S_/64 KV tiles

typedef unsigned short u16;
typedef unsigned int u32;
typedef __attribute__((ext_vector_type(2))) unsigned int u32x2;
typedef __attribute__((ext_vector_type(4))) unsigned short u16x4;
typedef __attribute__((ext_vector_type(8))) short bf16x8;
typedef __attribute__((ext_vector_type(4))) float f32x4;
typedef __attribute__((ext_vector_type(16))) float f32x16;

#define LOG2E 1.4426950408889634f

#if defined(__has_builtin)
#if __has_builtin(__builtin_amdgcn_permlane32_swap)
#define HAVE_PLS 1
#endif
#endif

__device__ __forceinline__ u16 f2bf(float f) {
  union { float f; uint32_t u; } x{f};
  uint32_t r = x.u + 0x7fffu + ((x.u >> 16) & 1u);
  return (u16)(r >> 16);
}

__device__ __forceinline__ float bf2f(u16 v) {
  union { uint32_t u; float f; } x{(uint32_t)v << 16};
  return x.f;
}

// pack hi16(a), hi16(b) -> dword (truncating bf16 pair) via v_perm_b32
__device__ __forceinline__ u32 pk2(float lo, float hi) {
  union { float f; u32 u; } a{lo}, b{hi};
  return __builtin_amdgcn_perm(b.u, a.u, 0x07060302u);
}

__device__ __forceinline__ float exp2fast(float x) {
#if __has_builtin(__builtin_amdgcn_exp2f)
  return __builtin_amdgcn_exp2f(x);
#else
  return exp2f(x);
#endif
}

__device__ __forceinline__ void gload16(const u16* g, u16* l) {
  __builtin_amdgcn_global_load_lds(
      (const __attribute__((address_space(1))) uint32_t*)g,
      (__attribute__((address_space(3))) uint32_t*)l, 16, 0, 0);
}

__device__ __forceinline__ int swz3(int r) { return (r & 7) ^ ((r >> 3) & 7); }

// ---------------- fused prep: cast x + all 6 weight transposes, one dispatch ----------------
__global__ __launch_bounds__(256) void prep_kernel(
    const float* __restrict__ x, u16* __restrict__ xb,
    const float* __restrict__ wq, const float* __restrict__ wk,
    const float* __restrict__ wv, const float* __restrict__ wo,
    const float* __restrict__ w1, const float* __restrict__ w2,
    u16* __restrict__ wqkvT, u16* __restrict__ woT,
    u16* __restrict__ w1T, u16* __restrict__ w2T) {
  int bid = blockIdx.x, tid = threadIdx.x;
  if (bid < 8192) {
    int i = bid * 256 + tid;
    f32x4 v = ((const f32x4*)x)[i];
    u16x4 o = { f2bf(v[0]), f2bf(v[1]), f2bf(v[2]), f2bf(v[3]) };
    ((u16x4*)xb)[i] = o;
    return;
  }
  bid -= 8192;
  const float* W; u16* WT; int K, N, bx, by;
  if (bid < 1024) {
    int which = bid >> 8;
    W  = (which == 0) ? wq : (which == 1) ? wk : (which == 2) ? wv : wo;
    WT = (which == 3) ? woT : (wqkvT + (size_t)which * 512 * 512);
    K = 512; N = 512;
    int r = bid & 255; bx = r & 15; by = r >> 4;
  } else if (bid < 2048) {
    int r = bid - 1024; W = w1; WT = w1T; K = 512; N = 2048;
    bx = r & 63; by = r >> 6;
  } else {
    int r = bid - 2048; W = w2; WT = w2T; K = 2048; N = 512;
    bx = r & 15; by = r >> 4;
  }
  __shared__ float t[32][33];
  int n0 = bx * 32, k0 = by * 32;
  int tx = tid & 31, ty = tid >> 5;
  #pragma unroll
  for (int i = 0; i < 4; i++)
    t[ty + 8*i][tx] = W[(size_t)(k0 + ty + 8*i) * N + n0 + tx];
  __syncthreads();
  #pragma unroll
  for (int i = 0; i < 4; i++)
    WT[(size_t)(n0 + ty + 8*i) * K + k0 + tx] = f2bf(t[tx][ty + 8*i]);
}

// ================= 128x128 BK=64 GEMM (O-proj / FFN2), 1 barrier per K-tile =================
// 8 LDS slots/row; swizzle slot' = slot ^ (row & 7); linear DMA dest + inverse-swizzled src.
__global__ __launch_bounds__(256) void gemm128_bk64_kernel(
    const u16* __restrict__ A, const u16* __restrict__ WT,
    const float* __restrict__ bias0, const u16* __restrict__ resB,
    u16* __restrict__ out0,
    float* __restrict__ partOut, int K, int N, int nx, int ypg) {
  __shared__ u16 lA[2][128 * 64];   // 32 KB
  __shared__ u16 lB[2][128 * 64];   // 32 KB
  __shared__ float lred[8];
  int tid = threadIdx.x;
  int lane = tid & 63, wid = tid >> 6;
  int wr = wid >> 1, wc = wid & 1;
  int lrow = lane & 15, kg = lane >> 4;

  int dd = blockIdx.x;
  int cc = dd & 7, jj = dd >> 3;
  int bx = jj % nx, by = cc * ypg + jj / nx;
  int m0 = by * 128, n0 = bx * 128;

  int r0 = tid >> 3;                               // 0..31 (+32j)
  int c0s = ((tid & 7) ^ (r0 & 7)) * 8;            // inverse-swizzled source col (j-invariant)
  const u16* agp = A  + (size_t)m0 * K;
  const u16* bgp = WT + (size_t)n0 * K;

  int aoff[4], boff[4];
  #pragma unroll
  for (int mi = 0; mi < 4; mi++) {
    int row = wr*64 + mi*16 + lrow;
    aoff[mi] = row*64 + ((kg ^ (row & 7)) * 8);
  }
  #pragma unroll
  for (int ni = 0; ni < 4; ni++) {
    int row = wc*64 + ni*16 + lrow;
    boff[ni] = row*64 + ((kg ^ (row & 7)) * 8);
  }

  f32x4 z = {0.f, 0.f, 0.f, 0.f};
  f32x4 acc[4][4];
  #pragma unroll
  for (int mi = 0; mi < 4; mi++)
    #pragma unroll
    for (int ni = 0; ni < 4; ni++) acc[mi][ni] = z;

#define STG64(buf, kt) do { \
    _Pragma("unroll") \
    for (int j = 0; j < 4; j++) { \
      gload16(agp + (size_t)(r0 + j*32) * K + (kt) + c0s, &lA[buf][(tid + j*256) * 8]); \
      gload16(bgp + (size_t)(r0 + j*32) * K + (kt) + c0s, &lB[buf][(tid + j*256) * 8]); \
    } \
  } while (0)

  STG64(0, 0);

  int nk = K / 64;
  int cur = 0;
  for (int t = 0; t < nk; t++) {
    __syncthreads();                       // single sync point per tile
    if (t + 1 < nk) STG64(cur ^ 1, (t + 1) * 64);
    #pragma unroll
    for (int kk = 0; kk < 2; kk++) {
      int xr = kk ? 32 : 0;
      bf16x8 af[4], bfv[4];
      #pragma unroll
      for (int mi = 0; mi < 4; mi++)
        af[mi] = *(const bf16x8*)&lA[cur][aoff[mi] ^ xr];
      #pragma unroll
      for (int ni = 0; ni < 4; ni++)
        bfv[ni] = *(const bf16x8*)&lB[cur][boff[ni] ^ xr];
      __builtin_amdgcn_s_setprio(1);
      #pragma unroll
      for (int mi = 0; mi < 4; mi++)
        #pragma unroll
        for (int ni = 0; ni < 4; ni++)
          acc[mi][ni] = __builtin_amdgcn_mfma_f32_16x16x32_bf16(af[mi], bfv[ni], acc[mi][ni], 0, 0, 0);
      __builtin_amdgcn_s_setprio(0);
    }
    cur ^= 1;
  }
#undef STG64

  float s_acc = 0.f, q_acc = 0.f;
  #pragma unroll
  for (int mi = 0; mi < 4; mi++)
    #pragma unroll
    for (int ni = 0; ni < 4; ni++) {
      int col = n0 + wc*64 + ni*16 + lrow;
      float bv = bias0[col];
      #pragma unroll
      for (int r = 0; r < 4; r++) {
        int row = m0 + wr*64 + mi*16 + kg*4 + r;
        size_t off = (size_t)row * N + col;
        float tv = acc[mi][ni][r] + bv + bf2f(resB[off]);
        out0[off] = f2bf(tv);
        s_acc += tv;
        q_acc += tv * tv;
      }
    }

  #pragma unroll
  for (int dsh = 1; dsh < 64; dsh <<= 1) {
    s_acc += __shfl_xor(s_acc, dsh);
    q_acc += __shfl_xor(q_acc, dsh);
  }
  if (lane == 0) { lred[wid*2] = s_acc; lred[wid*2+1] = q_acc; }
  __syncthreads();
  if (tid == 0) {
    int batch = by >> 3;
    int pidx = batch*32 + (by & 7)*nx + bx;
    partOut[pidx*2]   = lred[0]+lred[2]+lred[4]+lred[6];
    partOut[pidx*2+1] = lred[1]+lred[3]+lred[5]+lred[7];
  }
}

// ================= 128x128 BK=64 QKV GEMM (N=1536 split, Q scaled) =================
__global__ __launch_bounds__(256) void gemm128_bk64_qkv_kernel(
    const u16* __restrict__ A, const u16* __restrict__ WT,
    const float* __restrict__ bq, const float* __restrict__ bk,
    const float* __restrict__ bv,
    u16* __restrict__ Qb, u16* __restrict__ Kb, u16* __restrict__ Vb,
    int K, int nx, int ypg) {
  __shared__ u16 lA[2][128 * 64];
  __shared__ u16 lB[2][128 * 64];
  int tid = threadIdx.x;
  int lane = tid & 63, wid = tid >> 6;
  int wr = wid >> 1, wc = wid & 1;
  int lrow = lane & 15, kg = lane >> 4;

  int dd = blockIdx.x;
  int cc = dd & 7, jj = dd >> 3;
  int bx = jj % nx, by = cc * ypg + jj / nx;
  int m0 = by * 128, n0 = bx * 128;

  int r0 = tid >> 3;
  int c0s = ((tid & 7) ^ (r0 & 7)) * 8;
  const u16* agp = A  + (size_t)m0 * K;
  const u16* bgp = WT + (size_t)n0 * K;

  int aoff[4], boff[4];
  #pragma unroll
  for (int mi = 0; mi < 4; mi++) {
    int row = wr*64 + mi*16 + lrow;
    aoff[mi] = row*64 + ((kg ^ (row & 7)) * 8);
  }
  #pragma unroll
  for (int ni = 0; ni < 4; ni++) {
    int row = wc*64 + ni*16 + lrow;
    boff[ni] = row*64 + ((kg ^ (row & 7)) * 8);
  }

  f32x4 z = {0.f, 0.f, 0.f, 0.f};
  f32x4 acc[4][4];
  #pragma unroll
  for (int mi = 0; mi < 4; mi++)
    #pragma unroll
    for (int ni = 0; ni < 4; ni++) acc[mi][ni] = z;

#define STG64(buf, kt) do { \
    _Pragma("unroll") \
    for (int j = 0; j < 4; j++) { \
      gload16(agp + (size_t)(r0 + j*32) * K + (kt) + c0s, &lA[buf][(tid + j*256) * 8]); \
      gload16(bgp + (size_t)(r0 + j*32) * K + (kt) + c0s, &lB[buf][(tid + j*256) * 8]); \
    } \
  } while (0)

  STG64(0, 0);

  int nk = K / 64;
  int cur = 0;
  for (int t = 0; t < nk; t++) {
    __syncthreads();
    if (t + 1 < nk) STG64(cur ^ 1, (t + 1) * 64);
    #pragma unroll
    for (int kk = 0; kk < 2; kk++) {
      int xr = kk ? 32 : 0;
      bf16x8 af[4], bfv[4];
      #pragma unroll
      for (int mi = 0; mi < 4; mi++)
        af[mi] = *(const bf16x8*)&lA[cur][aoff[mi] ^ xr];
      #pragma unroll
      for (int ni = 0; ni < 4; ni++)
        bfv[ni] = *(const bf16x8*)&lB[cur][boff[ni] ^ xr];
      __builtin_amdgcn_s_setprio(1);
      #pragma unroll
      for (int mi = 0; mi < 4; mi++)
        #pragma unroll
        for (int ni = 0; ni < 4; ni++)
          acc[mi][ni] = __builtin_amdgcn_mfma_f32_16x16x32_bf16(af[mi], bfv[ni], acc[mi][ni], 0, 0, 0);
      __builtin_amdgcn_s_setprio(0);
    }
    cur ^= 1;
  }
#undef STG64

  // split epilogue: each 128-col block lies entirely in one 512-col segment
  int seg = n0 >> 9;                       // 0=Q, 1=K, 2=V
  const float* bp = (seg == 0) ? bq : (seg == 1) ? bk : bv;
  u16* op = (seg == 0) ? Qb : (seg == 1) ? Kb : Vb;
  float aeff = (seg == 0) ? 0.125f * LOG2E : 1.0f;

  #pragma unroll
  for (int mi = 0; mi < 4; mi++)
    #pragma unroll
    for (int ni = 0; ni < 4; ni++) {
      int col = n0 + wc*64 + ni*16 + lrow;
      int ocol = col & 511;
      float bvv = bp[ocol];
      #pragma unroll
      for (int r = 0; r < 4; r++) {
        int row = m0 + wr*64 + mi*16 + kg*4 + r;
        float v = (acc[mi][ni][r] + bvv) * aeff;
        op[(size_t)row * 512 + ocol] = f2bf(v);
      }
    }
}

// ================= 128x256 8-wave GEMM (FFN1): 2x barrier amortization =================
template<bool RELU>
__global__ __launch_bounds__(512, 4) void gemm128x256_kernel(
    const u16* __restrict__ A, const u16* __restrict__ WT,
    const float* __restrict__ bias0,
    u16* __restrict__ out0, int K, int N, int nx, int ypg) {
  __shared__ u16 lA[2][128 * 32];   // 16 KB
  __shared__ u16 lB[2][256 * 32];   // 32 KB
  int tid = threadIdx.x;
  int lane = tid & 63, wid = tid >> 6;
  int wr = wid >> 2, wc = wid & 3;          // 2M x 4N waves
  int lrow = lane & 15, kg = lane >> 4;

  int dd = blockIdx.x;
  int cc = dd & 7, jj = dd >> 3;
  int bx = jj % nx, by = cc * ypg + jj / nx;
  int m0 = by * 128, n0 = bx * 256;

  int r0 = tid >> 2;                               // 0..127
  int c0s = ((tid & 3) ^ ((r0 >> 1) & 3)) * 8;     // inverse-swizzled source col (+128 invariant)
  const u16* agp = A  + (size_t)m0 * K;
  const u16* bgp = WT + (size_t)n0 * K;

  int aoff[4], boff[4];
  #pragma unroll
  for (int mi = 0; mi < 4; mi++) {
    int row = wr*64 + mi*16 + lrow;
    aoff[mi] = row*32 + ((kg ^ ((row >> 1) & 3)) * 8);
  }
  #pragma unroll
  for (int ni = 0; ni < 4; ni++) {
    int row = wc*64 + ni*16 + lrow;                // 0..255
    boff[ni] = row*32 + ((kg ^ ((row >> 1) & 3)) * 8);
  }

  f32x4 z = {0.f, 0.f, 0.f, 0.f};
  f32x4 acc[4][4];
  #pragma unroll
  for (int mi = 0; mi < 4; mi++)
    #pragma unroll
    for (int ni = 0; ni < 4; ni++) acc[mi][ni] = z;

#define STG(buf, kt) do { \
    gload16(agp + (size_t)r0 * K + (kt) + c0s,         &lA[buf][tid * 8]); \
    gload16(bgp + (size_t)r0 * K + (kt) + c0s,         &lB[buf][tid * 8]); \
    gload16(bgp + (size_t)(r0 + 128) * K + (kt) + c0s, &lB[buf][4096 + tid * 8]); \
  } while (0)

  STG(0, 0);

  int nk = K / 32;
  int cur = 0;
  for (int t = 0; t < nk; t++) {
    __syncthreads();                 // single sync point per tile
    if (t + 1 < nk) STG(cur ^ 1, (t + 1) * 32);
    bf16x8 af[4], bfv[4];
    #pragma unroll
    for (int mi = 0; mi < 4; mi++)
      af[mi] = *(const bf16x8*)&lA[cur][aoff[mi]];
    #pragma unroll
    for (int ni = 0; ni < 4; ni++)
      bfv[ni] = *(const bf16x8*)&lB[cur][boff[ni]];
    __builtin_amdgcn_s_setprio(1);
    #pragma unroll
    for (int mi = 0; mi < 4; mi++)
      #pragma unroll
      for (int ni = 0; ni < 4; ni++)
        acc[mi][ni] = __builtin_amdgcn_mfma_f32_16x16x32_bf16(af[mi], bfv[ni], acc[mi][ni], 0, 0, 0);
    __builtin_amdgcn_s_setprio(0);
    cur ^= 1;
  }
#undef STG

  #pragma unroll
  for (int mi = 0; mi < 4; mi++)
    #pragma unroll
    for (int ni = 0; ni < 4; ni++) {
      int col = n0 + wc*64 + ni*16 + lrow;
      float bv = bias0[col];
      #pragma unroll
      for (int r = 0; r < 4; r++) {
        int row = m0 + wr*64 + mi*16 + kg*4 + r;
        float v = acc[mi][ni][r] + bv;
        if (RELU) v = fmaxf(v, 0.f);
        out0[(size_t)row * N + col] = f2bf(v);
      }
    }
}

// ---------------- flash attention v11: 8-wave blocks, 256 q-rows, shared K/V staging ----------------
__global__ __launch_bounds__(512) void attn_kernel(
    const u16* __restrict__ Q, const u16* __restrict__ Km,
    const u16* __restrict__ Vm, const float* __restrict__ mask,
    u16* __restrict__ ctx) {
  __shared__ u16 lK[2][4096];     // [key 64][dh 64], dword-swizzled, 128B rows
  __shared__ u16 lV[2][4096];     // [dh 64][key 64] transposed, dword-swizzled
  __shared__ float lBias[1024];
  int tid = threadIdx.x, lane = tid & 63, wid = tid >> 6;   // wid 0..7
  int la = lane & 31, hi = lane >> 5;
  int wg = blockIdx.x;
  int xcd = wg & 7, idx = wg >> 3;      // idx 0..63
  int bh = xcd * 16 + (idx & 15);
  int qt = idx >> 4;                    // 0..3 (256-row q tiles)
  int b = bh >> 3, h = bh & 7;
  bool vwave = (wid < 4);               // wave-uniform staging split
  int tid2 = tid & 255;                 // K-staging index for waves 4-7

  const u16* qp = Q + (size_t)(b*S_ + qt*256 + wid*32 + la) * D_ + h*DH_ + hi*8;
  bf16x8 qf[4];
  #pragma unroll
  for (int c = 0; c < 4; c++) qf[c] = *(const bf16x8*)(qp + c*16);

  int krow = tid2 >> 3;                 // 0..31 (K rows, +32 second call)
  int kcol = 8 * (tid2 & 7);
  int kc0 = kcol ^ (swz3(krow) << 3);
  int kc1 = kcol ^ (swz3(krow + 32) << 3);
  int va = tid & 7, vp = (tid >> 3) & 31;   // V staging map (waves 0-3: tid<256)
  const u16* kbase = Km + ((size_t)b*S_) * D_ + h*DH_;
  const u16* vbase = Vm + ((size_t)b*S_) * D_ + h*DH_ + 8*va;

#define STAGE_K(buf, tt) do { \
    const u16* kt_ = kbase + (size_t)(tt)*64*D_; \
    gload16(kt_ + (size_t)krow*D_ + kc0,        &lK[buf][tid2*8]); \
    gload16(kt_ + (size_t)(krow+32)*D_ + kc1,   &lK[buf][2048 + tid2*8]); \
  } while (0)
#define LOAD_V(tt) do { \
    const u16* vt_ = vbase + (size_t)((tt)*64 + 2*vp) * D_; \
    nv0 = *(const bf16x8*)vt_; nv1 = *(const bf16x8*)(vt_ + D_); \
  } while (0)
#define WRITE_V(buf) do { \
    u32* lVd_ = (u32*)lV[buf]; \
    _Pragma("unroll") \
    for (int jv = 0; jv < 8; jv++) { \
      int row_ = 8*va + jv; \
      u32 pv_ = (u32)(u16)nv0[jv] | ((u32)(u16)nv1[jv] << 16); \
      lVd_[row_*32 + (vp ^ (swz3(row_) << 2))] = pv_; \
    } \
  } while (0)

  int swk0 = swz3(la) << 2, swk1 = swz3(la + 32) << 2;
  f32x16 oc0, oc1;
  #pragma unroll
  for (int i = 0; i < 16; i++) { oc0[i] = 0.f; oc1[i] = 0.f; }
  float lsum = 0.f;

#define QKT(d0, d1, tt) do { \
    _Pragma("unroll") \
    for (int rq = 0; rq < 4; rq++) { \
      f32x4 bb0 = *(const f32x4*)&lBias[(tt)*64 + rq*8 + hi*4]; \
      f32x4 bb1 = *(const f32x4*)&lBias[(tt)*64 + 32 + rq*8 + hi*4]; \
      _Pragma("unroll") \
      for (int jj = 0; jj < 4; jj++) { d0[rq*4+jj] = bb0[jj]; d1[rq*4+jj] = bb1[jj]; } \
    } \
    { const u16* lkb_ = lK[(tt)&1]; \
      __builtin_amdgcn_s_setprio(1); \
      _Pragma("unroll") \
      for (int c_ = 0; c_ < 4; c_++) { \
        int dwb_ = c_*8 + hi*4; \
        bf16x8 kf0_ = *(const bf16x8*)&lkb_[la*64 + ((dwb_ ^ swk0) << 1)]; \
        bf16x8 kf1_ = *(const bf16x8*)&lkb_[(la+32)*64 + ((dwb_ ^ swk1) << 1)]; \
        d0 = __builtin_amdgcn_mfma_f32_32x32x16_bf16(kf0_, qf[c_], d0, 0, 0, 0); \
        d1 = __builtin_amdgcn_mfma_f32_32x32x16_bf16(kf1_, qf[c_], d1, 0, 0, 0); \
      } \
      __builtin_amdgcn_s_setprio(0); } \
  } while (0)

#define SOFTPV(s0v, s1v, tt) do { \
    float rsp_[4] = {0.f, 0.f, 0.f, 0.f}; \
    _Pragma("unroll") \
    for (int i_ = 0; i_ < 16; i_++) { float e_ = exp2fast(s0v[i_]); s0v[i_] = e_; rsp_[i_ & 3] += e_; } \
    _Pragma("unroll") \
    for (int i_ = 0; i_ < 16; i_++) { float e_ = exp2fast(s1v[i_]); s1v[i_] = e_; rsp_[i_ & 3] += e_; } \
    lsum += (rsp_[0] + rsp_[1]) + (rsp_[2] + rsp_[3]); \
    { const u16* lvb_ = lV[(tt)&1]; \
      __builtin_amdgcn_s_setprio(1); \
      _Pragma("unroll") \
      for (int cc_ = 0; cc_ < 4; cc_++) { \
        const int base_ = 8 * (cc_ & 1); \
        float pv_[8]; \
        _Pragma("unroll") \
        for (int k_ = 0; k_ < 8; k_++) pv_[k_] = (cc_ < 2) ? s0v[base_ + k_] : s1v[base_ + k_]; \
        u32 a0_ = pk2(pv_[0], pv_[1]); \
        u32 a1_ = pk2(pv_[2], pv_[3]); \
        u32 b0_ = pk2(pv_[4], pv_[5]); \
        u32 b1_ = pk2(pv_[6], pv_[7]); \
        union { u32 u[4]; bf16x8 v; } pf_; \
        PEXCH(pf_, a0_, a1_, b0_, b1_); \
        _Pragma("unroll") \
        for (int vb_ = 0; vb_ < 2; vb_++) { \
          int row_ = vb_*32 + la; \
          int dwv_ = (cc_*8 + hi*4) ^ (swz3(row_) << 2); \
          bf16x8 vf_ = *(const bf16x8*)&lvb_[row_*64 + (dwv_ << 1)]; \
          if (vb_ == 0) oc0 = __builtin_amdgcn_mfma_f32_32x32x16_bf16(pf_.v, vf_, oc0, 0, 0, 0); \
          else          oc1 = __builtin_amdgcn_mfma_f32_32x32x16_bf16(pf_.v, vf_, oc1, 0, 0, 0); \
        } \
      } \
      __builtin_amdgcn_s_setprio(0); } \
  } while (0)

#ifdef HAVE_PLS
#define PEXCH(pf_, a0_, a1_, b0_, b1_) do { \
    u32x2 r0_ = __builtin_amdgcn_permlane32_swap(a0_, b0_, false, false); \
    u32x2 r1_ = __builtin_amdgcn_permlane32_swap(a1_, b1_, false, false); \
    pf_.u[0] = r0_[0]; pf_.u[1] = r1_[0]; pf_.u[2] = r0_[1]; pf_.u[3] = r1_[1]; \
  } while (0)
#else
#define PEXCH(pf_, a0_, a1_, b0_, b1_) do { \
    u32 sd0_ = hi ? a0_ : b0_, sd1_ = hi ? a1_ : b1_; \
    u32 x0_ = (u32)__shfl_xor((int)sd0_, 32); \
    u32 x1_ = (u32)__shfl_xor((int)sd1_, 32); \
    pf_.u[0] = hi ? x0_ : a0_; \
    pf_.u[1] = hi ? x1_ : a1_; \
    pf_.u[2] = hi ? b0_ : x0_; \
    pf_.u[3] = hi ? b1_ : x1_; \
  } while (0)
#endif

  // ---- prologue: waves 0-3 stage V0 + bias, load V1; waves 4-7 DMA K0,K1 ----
  bf16x8 nv0, nv1;
  if (vwave) {
    f32x4 mv = ((const f32x4*)(mask + (size_t)b*S_))[tid];
    f32x4 bv;
    #pragma unroll
    for (int jj = 0; jj < 4; jj++) bv[jj] = mv[jj] * (-1.0e9f * LOG2E);
    ((f32x4*)lBias)[tid] = bv;
    LOAD_V(0);
    WRITE_V(0);
    LOAD_V(1);
  } else {
    STAGE_K(0, 0);
    STAGE_K(1, 1);
  }
  __syncthreads();

  f32x16 sA0, sA1, sB0, sB1;
  QKT(sA0, sA1, 0);
  __syncthreads();          // all waves done reading lK[0] before iter0 re-DMAs it

  // ---- pipelined main loop, unrolled by 2 (A/B score states) ----
  for (int t = 0; t < NT_; t += 2) {
    if (!vwave) { if (t + 2 < NT_) STAGE_K(t & 1, t + 2); }
    if (vwave) {
      WRITE_V((t + 1) & 1);
      if (t + 2 < NT_) LOAD_V(t + 2);
    }
    QKT(sB0, sB1, t + 1);
    SOFTPV(sA0, sA1, t);
    __syncthreads();
    {
      int u = t + 1;
      if (!vwave) { if (u + 2 < NT_) STAGE_K(u & 1, u + 2); }
      if (vwave) {
        if (u + 1 < NT_) WRITE_V((u + 1) & 1);
        if (u + 2 < NT_) LOAD_V(u + 2);
      }
      if (u + 1 < NT_) QKT(sA0, sA1, u + 1);
      SOFTPV(sB0, sB1, u);
      __syncthreads();
    }
  }
#undef STAGE_K
#undef LOAD_V
#undef WRITE_V
#undef QKT
#undef SOFTPV
#undef PEXCH

  // ---- epilogue ----
  lsum += __shfl_xor(lsum, 32);
  float linv = 1.f / lsum;
  #pragma unroll
  for (int r = 0; r < 16; r++) {
    int qr = (r&3) + 8*(r>>2) + 4*hi;
    float lr = __shfl(linv, qr);
    size_t rowoff = (size_t)(b*S_ + qt*256 + wid*32 + qr) * D_ + h*DH_;
    ctx[rowoff + la]      = f2bf(oc0[r] * lr);
    ctx[rowoff + 32 + la] = f2bf(oc1[r] * lr);
  }
}

// ---------------- LayerNorm apply (bf16 input; partials from GEMM epilogue) ----------------
template<bool WB, bool WF>
__global__ __launch_bounds__(256) void ln_apply_kernel(
    const u16* __restrict__ r, const float* __restrict__ part,
    const float* __restrict__ w, const float* __restrict__ bb,
    float* __restrict__ outF, u16* __restrict__ outB) {
  int b = blockIdx.y, c = blockIdx.x, tid = threadIdx.x;
  float s = 0.f, q = 0.f;
  for (int i = 0; i < 32; i++) { s += part[(b*32+i)*2]; q += part[(b*32+i)*2+1]; }
  const float inv = 1.f / (float)SD_;
  float mean = s * inv;
  float var = q * inv - mean * mean;
  float rs = rsqrtf(var + 1e-5f);
  size_t base = (size_t)b * SD_;
  #pragma unroll
  for (int i = 0; i < 8; i++) {
    int li4 = c*2048 + i*256 + tid;   // 4-elem index within slab
    u16x4 rv = ((const u16x4*)(r + base))[li4];
    f32x4 wv = ((const f32x4*)w)[li4];
    f32x4 bv = ((const f32x4*)bb)[li4];
    f32x4 ov;
    #pragma unroll
    for (int jj = 0; jj < 4; jj++) ov[jj] = (bf2f(rv[jj]) - mean) * rs * wv[jj] + bv[jj];
    if (WF) ((f32x4*)(outF + base))[li4] = ov;
    if (WB) {
      u16x4 ub = { f2bf(ov[0]), f2bf(ov[1]), f2bf(ov[2]), f2bf(ov[3]) };
      ((u16x4*)(outB + base))[li4] = ub;
    }
  }
}

// ---------------- launch ----------------
extern "C" void kernel_launch(void* const* d_in, const int* in_sizes, int n_in,
                              void* d_out, int out_size, void* d_ws, size_t ws_size,
                              hipStream_t stream) {
  (void)in_sizes; (void)n_in; (void)out_size; (void)ws_size;
  const float* x    = (const float*)d_in[0];
  const float* mask = (const float*)d_in[1];
  const float* wq = (const float*)d_in[2];
  const float* bq = (const float*)d_in[3];
  const float* wk = (const float*)d_in[4];
  const float* bk = (const float*)d_in[5];
  const float* wv = (const float*)d_in[6];
  const float* bv = (const float*)d_in[7];
  const float* wo = (const float*)d_in[8];
  const float* bo = (const float*)d_in[9];
  const float* w1 = (const float*)d_in[10];
  const float* b1 = (const float*)d_in[11];
  const float* w2 = (const float*)d_in[12];
  const float* b2 = (const float*)d_in[13];
  const float* ln1w = (const float*)d_in[14];
  const float* ln1b = (const float*)d_in[15];
  const float* ln2w = (const float*)d_in[16];
  const float* ln2b = (const float*)d_in[17];
  float* out = (float*)d_out;

  char* ws = (char*)d_ws;
  const size_t MB = 1ull << 20;
  u16*   xb    = (u16*)(ws + 0);
  u16*   Qb    = (u16*)(ws + 16*MB);
  u16*   Kb    = (u16*)(ws + 32*MB);
  u16*   Vb    = (u16*)(ws + 48*MB);
  u16*   ctxb  = (u16*)(ws + 64*MB);
  u16*   res1b = (u16*)(ws + 80*MB);
  u16*   out1b = (u16*)(ws + 0);        // reuse xb (xb fully consumed by O-proj residual read)
  u16*   ffn1  = (u16*)(ws + 16*MB);    // reuse Q/K/V/ctx (dead after O-proj)
  u16*   res2b = (u16*)(ws + 112*MB);
  float* part  = (float*)(ws + 144*MB);
  u16*   wqkvT = (u16*)(ws + 145*MB);   // [1536][512] bf16
  u16*   woT   = (u16*)(ws + 147*MB);
  u16*   w1T   = (u16*)(ws + 148*MB);
  u16*   w2T   = (u16*)(ws + 150*MB);

  // fused prep: cast x + all 6 weight transposes
  prep_kernel<<<11264, 256, 0, stream>>>(
      x, xb, wq, wk, wv, wo, w1, w2, wqkvT, woT, w1T, w2T);

  // fused QKV projection: 128^2 BK=64 split kernel, grid 1536 (nx=12, ypg=16)
  gemm128_bk64_qkv_kernel<<<1536, 256, 0, stream>>>(
      xb, wqkvT, bq, bk, bv, Qb, Kb, Vb, 512, 12, 16);

  attn_kernel<<<512, 512, 0, stream>>>(Qb, Kb, Vb, mask, ctxb);

  // O-proj: 128^2 BK=64, residual = xb (bf16), bf16 out + fused LN1 partials. grid 512
  gemm128_bk64_kernel<<<512, 256, 0, stream>>>(
      ctxb, woT, bo, xb, res1b, part, 512, 512, 4, 16);

  ln_apply_kernel<true,false><<<dim3(64,16), 256, 0, stream>>>(
      res1b, part, ln1w, ln1b, nullptr, out1b);

  // FFN1: 128x256 8-wave + ReLU, grid 1024 (nx=8, ypg=16)
  gemm128x256_kernel<true><<<1024, 512, 0, stream>>>(
      out1b, w1T, b1, ffn1, 512, 2048, 8, 16);

  // FFN2: 128^2 BK=64, residual = out1b (bf16), bf16 out + fused LN2 partials. grid 512
  gemm128_bk64_kernel<<<512, 256, 0, stream>>>(
      ffn1, w2T, b2, out1b, res2b, part, 2048, 512, 4, 16);

  ln_apply_kernel<false,true><<<dim3(64,16), 256, 0, stream>>>(
      res2b, part, ln2w, ln2b, out, nullptr);
}